// Round 2
// baseline (1206.020 us; speedup 1.0000x reference)
//
#include <hip/hip_runtime.h>

typedef unsigned short u16;
typedef __bf16 bf16x8 __attribute__((ext_vector_type(8)));
typedef float f32x4 __attribute__((ext_vector_type(4)));

#define S_LEN 2048
#define HID 5120
#define NHEAD 40
#define NKVH 8
#define HD 128
#define QKV_COLS 7168   // (40 + 2*8) * 128
#define GQA 5

// RNE f32 -> bf16 (values are finite; no NaN handling needed)
__device__ __forceinline__ u16 f2bf(float f) {
  unsigned u = __float_as_uint(f);
  u += 0x7FFFu + ((u >> 16) & 1u);
  return (u16)(u >> 16);
}

// async global->LDS, 16B per lane; LDS base must be wave-uniform
__device__ __forceinline__ void async16(void* lds, const void* g) {
  __builtin_amdgcn_global_load_lds(
      (const __attribute__((address_space(1))) unsigned int*)g,
      (__attribute__((address_space(3))) unsigned int*)lds, 16, 0, 0);
}

// ---------- f32 -> bf16 elementwise convert (float4 -> 4x bf16) ----------
__global__ void k_f32_to_bf16(const float4* __restrict__ in, uint2* __restrict__ out, int n4) {
  int i = blockIdx.x * blockDim.x + threadIdx.x;
  int stride = gridDim.x * blockDim.x;
  for (; i < n4; i += stride) {
    float4 v = in[i];
    uint2 o;
    o.x = (unsigned)f2bf(v.x) | ((unsigned)f2bf(v.y) << 16);
    o.y = (unsigned)f2bf(v.z) | ((unsigned)f2bf(v.w) << 16);
    out[i] = o;
  }
}

// ---------- C[M,N] f32 = A[M,K] bf16 * B[N,K]^T bf16  (m97 structure) ----------
// 128x128 tile, BK=32, 4 waves (each 64x64), 16x16x32 MFMA, global_load_lds w=16.
__global__ __launch_bounds__(256)
void k_gemm_bt(const u16* __restrict__ A, const u16* __restrict__ B,
               float* __restrict__ C, int M, int N, int K) {
  __shared__ __align__(16) u16 As[128 * 32];
  __shared__ __align__(16) u16 Bs[128 * 32];
  const int tid = threadIdx.x;
  const int wave = tid >> 6, lane = tid & 63;
  const int l15 = lane & 15, l4 = lane >> 4;
  const int wr = wave >> 1, wc = wave & 1;
  const int row0 = blockIdx.y * 128;
  const int col0 = blockIdx.x * 128;
  const int lrow = lane >> 2, lq = lane & 3;   // staging: 16 rows x 4 chunks of 16B

  f32x4 acc[4][4] = {};

  const int nk = K >> 5;
  for (int kt = 0; kt < nk; ++kt) {
    const int k0 = kt << 5;
#pragma unroll
    for (int c = 0; c < 2; ++c) {
      const int seg = wave * 2 + c;            // wave-uniform segment of 16 rows
      async16(As + seg * 512, A + (size_t)(row0 + seg * 16 + lrow) * K + k0 + lq * 8);
      async16(Bs + seg * 512, B + (size_t)(col0 + seg * 16 + lrow) * K + k0 + lq * 8);
    }
    __syncthreads();   // compiler drains vmcnt before s_barrier
    bf16x8 af[4], bfr[4];
    const u16* pa = As + (wr * 64 + l15) * 32 + l4 * 8;
    const u16* pb = Bs + (wc * 64 + l15) * 32 + l4 * 8;
#pragma unroll
    for (int m = 0; m < 4; ++m) af[m] = *(const bf16x8*)(pa + m * 512);
#pragma unroll
    for (int n = 0; n < 4; ++n) bfr[n] = *(const bf16x8*)(pb + n * 512);
#pragma unroll
    for (int m = 0; m < 4; ++m)
#pragma unroll
      for (int n = 0; n < 4; ++n)
        acc[m][n] = __builtin_amdgcn_mfma_f32_16x16x32_bf16(af[m], bfr[n], acc[m][n], 0, 0, 0);
    __syncthreads();
  }
  // C/D layout (m89-verified): col = lane&15, row = (lane>>4)*4 + reg
#pragma unroll
  for (int m = 0; m < 4; ++m)
#pragma unroll
    for (int n = 0; n < 4; ++n)
#pragma unroll
      for (int r = 0; r < 4; ++r) {
        int row = row0 + wr * 64 + m * 16 + l4 * 4 + r;
        int col = col0 + wc * 64 + n * 16 + l15;
        C[(size_t)row * N + col] = acc[m][n][r];
      }
}

// ---------- RoPE (neox) + per-head RMSNorm; Q additionally pre-scaled by D^-0.5 ----------
// one wave per (s, head-row); lane d in [0,64) handles the pair (d, d+64)
__global__ void k_rope_norm(const float* __restrict__ qkv, const int* __restrict__ pos,
                            const float* __restrict__ wqk,
                            u16* __restrict__ qo, u16* __restrict__ ko) {
  const int wid = (blockIdx.x * blockDim.x + threadIdx.x) >> 6;
  const int lane = threadIdx.x & 63;
  const int s = wid / 48;
  const int r = wid - s * 48;          // 0..39 = q heads, 40..47 = k heads
  const float* src;
  u16* dst;
  const bool isq = (r < NHEAD);
  if (isq) {
    src = qkv + (size_t)s * QKV_COLS + r * HD;
    dst = qo + (size_t)s * (NHEAD * HD) + r * HD;
  } else {
    int kv = r - NHEAD;
    src = qkv + (size_t)s * QKV_COLS + HID + kv * HD;
    dst = ko + (size_t)s * (NKVH * HD) + kv * HD;
  }
  float x1 = src[lane], x2 = src[lane + 64];
  float p = (float)pos[s];
  // inv_freq = theta^(-d/64) = exp2(-d * log2(theta)/64)
  float ang = p * exp2f(-(float)lane * (18.931568569324174f / 64.0f));
  float sn, cs;
  sincosf(ang, &sn, &cs);
  float y1 = x1 * cs - x2 * sn;
  float y2 = x2 * cs + x1 * sn;
  float ss = y1 * y1 + y2 * y2;
#pragma unroll
  for (int off = 32; off > 0; off >>= 1) ss += __shfl_xor(ss, off);
  float rms = rsqrtf(ss * (1.0f / 128.0f) + 1e-5f);
  float sc = isq ? 0.08838834764831843f : 1.0f;   // fold attention scale into Q
  dst[lane] = f2bf(y1 * rms * wqk[lane] * sc);
  dst[lane + 64] = f2bf(y2 * rms * wqk[lane + 64] * sc);
}

// ---------- V: [s][6144 + kvh*128 + d] f32 -> Vt[kvh][d][s] bf16 ----------
__global__ void k_vtrans(const float* __restrict__ qkv, u16* __restrict__ vt) {
  __shared__ float t[32][129];   // +1 pad: conflict-free transposed read
  const int s0 = blockIdx.x * 32;
  const int kv = blockIdx.y;
  for (int i = threadIdx.x; i < 32 * 128; i += 256) {
    int sr = i >> 7, d = i & 127;
    t[sr][d] = qkv[(size_t)(s0 + sr) * QKV_COLS + (HID + NKVH * HD) + kv * HD + d];
  }
  __syncthreads();
  for (int i = threadIdx.x; i < 32 * 128; i += 256) {
    int d = i >> 5, sc = i & 31;
    vt[((size_t)kv * HD + d) * S_LEN + s0 + sc] = f2bf(t[sc][d]);
  }
}

// ---------- causal GQA flash attention ----------
// grid (32 q-tiles of 64, 40 heads), 4 waves; wave owns 16 q-rows.
// Q pre-scaled; K/V read direct from global (L2-resident, 8 MB total).
__global__ __launch_bounds__(256)
void k_attn(const u16* __restrict__ Q, const u16* __restrict__ Kb,
            const u16* __restrict__ Vt, u16* __restrict__ ctx) {
  __shared__ __align__(16) u16 Plds[4][16][72];   // per-wave P tile, padded stride
  const int h = blockIdx.y;
  const int kvh = h / GQA;
  const int qt = blockIdx.x;
  const int wave = threadIdx.x >> 6, lane = threadIdx.x & 63;
  const int l15 = lane & 15, l4 = lane >> 4;
  const int qrow0 = qt * 64 + wave * 16;

  bf16x8 qf[4];
#pragma unroll
  for (int c = 0; c < 4; ++c)
    qf[c] = *(const bf16x8*)(Q + (size_t)(qrow0 + l15) * HID + h * HD + c * 32 + l4 * 8);

  float m_run[4] = {-1e30f, -1e30f, -1e30f, -1e30f};
  float l_run[4] = {0.f, 0.f, 0.f, 0.f};
  f32x4 oacc[8] = {};
  const f32x4 fzero = {0.f, 0.f, 0.f, 0.f};

  for (int kt = 0; kt <= qt; ++kt) {
    const int key0 = kt * 64;
    f32x4 sa[4];
#pragma unroll
    for (int n = 0; n < 4; ++n) sa[n] = fzero;
    // S = Q (16xD) x K^T (Dx64)
#pragma unroll
    for (int n = 0; n < 4; ++n) {
      const u16* kp = Kb + (size_t)(key0 + n * 16 + l15) * (NKVH * HD) + kvh * HD + l4 * 8;
#pragma unroll
      for (int c = 0; c < 4; ++c) {
        bf16x8 kf = *(const bf16x8*)(kp + c * 32);
        sa[n] = __builtin_amdgcn_mfma_f32_16x16x32_bf16(qf[c], kf, sa[n], 0, 0, 0);
      }
    }
    if (kt == qt) {   // causal mask within diagonal tile
#pragma unroll
      for (int n = 0; n < 4; ++n)
#pragma unroll
        for (int r = 0; r < 4; ++r)
          if (n * 16 + l15 > wave * 16 + l4 * 4 + r) sa[n][r] = -1e30f;
    }
    // online softmax; row lives in a 16-lane group (row = (l>>4)*4 + r)
    float mnew[4], corr[4];
#pragma unroll
    for (int r = 0; r < 4; ++r) {
      float v = fmaxf(fmaxf(sa[0][r], sa[1][r]), fmaxf(sa[2][r], sa[3][r]));
#pragma unroll
      for (int off = 1; off < 16; off <<= 1) v = fmaxf(v, __shfl_xor(v, off));
      mnew[r] = fmaxf(m_run[r], v);
      corr[r] = __expf(m_run[r] - mnew[r]);
      m_run[r] = mnew[r];
    }
    float pr[4][4];
#pragma unroll
    for (int n = 0; n < 4; ++n)
#pragma unroll
      for (int r = 0; r < 4; ++r) pr[n][r] = __expf(sa[n][r] - mnew[r]);
#pragma unroll
    for (int r = 0; r < 4; ++r) {
      float sum = pr[0][r] + pr[1][r] + pr[2][r] + pr[3][r];
#pragma unroll
      for (int off = 1; off < 16; off <<= 1) sum += __shfl_xor(sum, off);
      l_run[r] = l_run[r] * corr[r] + sum;
    }
#pragma unroll
    for (int f = 0; f < 8; ++f)
#pragma unroll
      for (int r = 0; r < 4; ++r) oacc[f][r] *= corr[r];
    // P -> bf16 via per-wave LDS slice (C-layout -> A-layout redistribution)
#pragma unroll
    for (int n = 0; n < 4; ++n)
#pragma unroll
      for (int r = 0; r < 4; ++r)
        Plds[wave][l4 * 4 + r][n * 16 + l15] = f2bf(pr[n][r]);
    // Wave-synchronous LDS handoff: per-thread write/read sets can be disjoint,
    // so force ordering + drain all lanes' ds_writes before the cross-lane read.
    asm volatile("s_waitcnt lgkmcnt(0)" ::: "memory");
    // O += P (16x64) x V (64xD)
#pragma unroll
    for (int c2 = 0; c2 < 2; ++c2) {
      bf16x8 pa = *(const bf16x8*)(&Plds[wave][l15][c2 * 32 + l4 * 8]);
#pragma unroll
      for (int f = 0; f < 8; ++f) {
        bf16x8 vf = *(const bf16x8*)(Vt + ((size_t)kvh * HD + f * 16 + l15) * S_LEN + key0 + c2 * 32 + l4 * 8);
        oacc[f] = __builtin_amdgcn_mfma_f32_16x16x32_bf16(pa, vf, oacc[f], 0, 0, 0);
      }
    }
  }
#pragma unroll
  for (int f = 0; f < 8; ++f)
#pragma unroll
    for (int r = 0; r < 4; ++r) {
      float val = oacc[f][r] / l_run[r];
      int row = qrow0 + l4 * 4 + r;
      ctx[(size_t)row * HID + h * HD + f * 16 + l15] = f2bf(val);
    }
}

extern "C" void kernel_launch(void* const* d_in, const int* in_sizes, int n_in,
                              void* d_out, int out_size, void* d_ws, size_t ws_size,
                              hipStream_t stream) {
  (void)in_sizes; (void)n_in; (void)out_size; (void)ws_size;
  const int* positions = (const int*)d_in[0];
  const float* hs = (const float*)d_in[1];
  const float* Wqkv = (const float*)d_in[2];
  const float* Wo = (const float*)d_in[3];
  const float* wqk = (const float*)d_in[4];
  float* out = (float*)d_out;

  // workspace layout (aliased where lifetimes allow); total = 205,520,896 B
  char* ws = (char*)d_ws;
  u16* Wqkv_b = (u16*)ws;                  // [0, 73400320)  dead after GEMM1
  u16* q_b   = (u16*)ws;                   // reuse: [0, 20971520)
  u16* k_b   = (u16*)(ws + 20971520);      // [.., 25165824)
  u16* vt_b  = (u16*)(ws + 25165824);      // [.., 29360128)
  u16* Wo_b  = (u16*)(ws + 73400320);      // [.., 125829120)
  u16* hs_b  = (u16*)(ws + 125829120);     // [.., 146800640)  dead after GEMM1
  u16* ctx_b = hs_b;                       // reuse
  float* qkv = (float*)(ws + 146800640);   // [.., 205520896)

  k_f32_to_bf16<<<2048, 256, 0, stream>>>((const float4*)hs, (uint2*)hs_b, (S_LEN * HID) / 4);
  k_f32_to_bf16<<<2048, 256, 0, stream>>>((const float4*)Wqkv, (uint2*)Wqkv_b, (QKV_COLS * HID) / 4);
  k_f32_to_bf16<<<2048, 256, 0, stream>>>((const float4*)Wo, (uint2*)Wo_b, (HID * HID) / 4);

  k_gemm_bt<<<dim3(QKV_COLS / 128, S_LEN / 128), 256, 0, stream>>>(hs_b, Wqkv_b, qkv, S_LEN, QKV_COLS, HID);

  k_rope_norm<<<(S_LEN * 48) / 4, 256, 0, stream>>>(qkv, positions, wqk, q_b, k_b);
  k_vtrans<<<dim3(S_LEN / 32, NKVH), 256, 0, stream>>>(qkv, vt_b);

  k_attn<<<dim3(S_LEN / 64, NHEAD), 256, 0, stream>>>(q_b, k_b, vt_b, ctx_b);

  k_gemm_bt<<<dim3(HID / 128, S_LEN / 128), 256, 0, stream>>>(ctx_b, Wo_b, out, S_LEN, HID, HID);
}

// Round 3
// 763.637 us; speedup vs baseline: 1.5793x; 1.5793x over previous
//
#include <hip/hip_runtime.h>

typedef unsigned short u16;
typedef __bf16 bf16x8 __attribute__((ext_vector_type(8)));
typedef float f32x4 __attribute__((ext_vector_type(4)));

#define S_LEN 2048
#define HID 5120
#define NHEAD 40
#define NKVH 8
#define HD 128
#define QKV_COLS 7168   // (40 + 2*8) * 128
#define GQA 5
#define QBLK 128
#define KVBLK 64

// RNE f32 -> bf16 (values are finite; no NaN handling needed)
__device__ __forceinline__ u16 f2bf(float f) {
  unsigned u = __float_as_uint(f);
  u += 0x7FFFu + ((u >> 16) & 1u);
  return (u16)(u >> 16);
}

// async global->LDS, 16B per lane; LDS base must be wave-uniform
__device__ __forceinline__ void async16(void* lds, const void* g) {
  __builtin_amdgcn_global_load_lds(
      (const __attribute__((address_space(1))) unsigned int*)g,
      (__attribute__((address_space(3))) unsigned int*)lds, 16, 0, 0);
}

// ---------- f32 -> bf16 elementwise convert (float4 -> 4x bf16) ----------
__global__ void k_f32_to_bf16(const float4* __restrict__ in, uint2* __restrict__ out, int n4) {
  int i = blockIdx.x * blockDim.x + threadIdx.x;
  int stride = gridDim.x * blockDim.x;
  for (; i < n4; i += stride) {
    float4 v = in[i];
    uint2 o;
    o.x = (unsigned)f2bf(v.x) | ((unsigned)f2bf(v.y) << 16);
    o.y = (unsigned)f2bf(v.z) | ((unsigned)f2bf(v.w) << 16);
    out[i] = o;
  }
}

// ---------- C[M,N] f32 = A[M,K] bf16 * B[N,K]^T bf16  (m97 structure) ----------
__global__ __launch_bounds__(256)
void k_gemm_bt(const u16* __restrict__ A, const u16* __restrict__ B,
               float* __restrict__ C, int M, int N, int K) {
  __shared__ __align__(16) u16 As[128 * 32];
  __shared__ __align__(16) u16 Bs[128 * 32];
  const int tid = threadIdx.x;
  const int wave = tid >> 6, lane = tid & 63;
  const int l15 = lane & 15, l4 = lane >> 4;
  const int wr = wave >> 1, wc = wave & 1;
  const int row0 = blockIdx.y * 128;
  const int col0 = blockIdx.x * 128;
  const int lrow = lane >> 2, lq = lane & 3;

  f32x4 acc[4][4] = {};

  const int nk = K >> 5;
  for (int kt = 0; kt < nk; ++kt) {
    const int k0 = kt << 5;
#pragma unroll
    for (int c = 0; c < 2; ++c) {
      const int seg = wave * 2 + c;
      async16(As + seg * 512, A + (size_t)(row0 + seg * 16 + lrow) * K + k0 + lq * 8);
      async16(Bs + seg * 512, B + (size_t)(col0 + seg * 16 + lrow) * K + k0 + lq * 8);
    }
    __syncthreads();
    bf16x8 af[4], bfr[4];
    const u16* pa = As + (wr * 64 + l15) * 32 + l4 * 8;
    const u16* pb = Bs + (wc * 64 + l15) * 32 + l4 * 8;
#pragma unroll
    for (int m = 0; m < 4; ++m) af[m] = *(const bf16x8*)(pa + m * 512);
#pragma unroll
    for (int n = 0; n < 4; ++n) bfr[n] = *(const bf16x8*)(pb + n * 512);
#pragma unroll
    for (int m = 0; m < 4; ++m)
#pragma unroll
      for (int n = 0; n < 4; ++n)
        acc[m][n] = __builtin_amdgcn_mfma_f32_16x16x32_bf16(af[m], bfr[n], acc[m][n], 0, 0, 0);
    __syncthreads();
  }
#pragma unroll
  for (int m = 0; m < 4; ++m)
#pragma unroll
    for (int n = 0; n < 4; ++n)
#pragma unroll
      for (int r = 0; r < 4; ++r) {
        int row = row0 + wr * 64 + m * 16 + l4 * 4 + r;
        int col = col0 + wc * 64 + n * 16 + l15;
        C[(size_t)row * N + col] = acc[m][n][r];
      }
}

// ---------- RoPE (neox) + per-head RMSNorm ----------
__global__ void k_rope_norm(const float* __restrict__ qkv, const int* __restrict__ pos,
                            const float* __restrict__ wqk,
                            u16* __restrict__ qo, u16* __restrict__ ko) {
  const int wid = (blockIdx.x * blockDim.x + threadIdx.x) >> 6;
  const int lane = threadIdx.x & 63;
  const int s = wid / 48;
  const int r = wid - s * 48;
  const float* src;
  u16* dst;
  const bool isq = (r < NHEAD);
  if (isq) {
    src = qkv + (size_t)s * QKV_COLS + r * HD;
    dst = qo + (size_t)s * (NHEAD * HD) + r * HD;
  } else {
    int kv = r - NHEAD;
    src = qkv + (size_t)s * QKV_COLS + HID + kv * HD;
    dst = ko + (size_t)s * (NKVH * HD) + kv * HD;
  }
  float x1 = src[lane], x2 = src[lane + 64];
  float p = (float)pos[s];
  float ang = p * exp2f(-(float)lane * (18.931568569324174f / 64.0f));
  float sn, cs;
  sincosf(ang, &sn, &cs);
  float y1 = x1 * cs - x2 * sn;
  float y2 = x2 * cs + x1 * sn;
  float ss = y1 * y1 + y2 * y2;
#pragma unroll
  for (int off = 32; off > 0; off >>= 1) ss += __shfl_xor(ss, off);
  float rms = rsqrtf(ss * (1.0f / 128.0f) + 1e-5f);
  float sc = isq ? 0.08838834764831843f : 1.0f;
  dst[lane] = f2bf(y1 * rms * wqk[lane] * sc);
  dst[lane + 64] = f2bf(y2 * rms * wqk[lane + 64] * sc);
}

// ---------- V: [s][6144 + kvh*128 + d] f32 -> Vt[kvh][d][s] bf16 ----------
__global__ void k_vtrans(const float* __restrict__ qkv, u16* __restrict__ vt) {
  __shared__ float t[32][129];
  const int s0 = blockIdx.x * 32;
  const int kv = blockIdx.y;
  for (int i = threadIdx.x; i < 32 * 128; i += 256) {
    int sr = i >> 7, d = i & 127;
    t[sr][d] = qkv[(size_t)(s0 + sr) * QKV_COLS + (HID + NKVH * HD) + kv * HD + d];
  }
  __syncthreads();
  for (int i = threadIdx.x; i < 32 * 128; i += 256) {
    int d = i >> 5, sc = i & 31;
    vt[((size_t)kv * HD + d) * S_LEN + s0 + sc] = f2bf(t[sc][d]);
  }
}

// ---------- causal GQA flash attention (flash structure, LDS-staged K/V) ----------
// grid (16 q-tiles of 128, 40 heads), 4 waves; wave owns 32 q-rows.
// K [64][128] and V^T [128][64] tiles double-buffered in LDS, XOR-swizzled
// (rule 21: linear LDS dest for global_load_lds + inverse-swizzled global src
//  + swizzled ds_read). P exchanged via per-wave swizzled LDS slice.
__global__ __launch_bounds__(256, 2)
void k_attn(const u16* __restrict__ Q, const u16* __restrict__ Kb,
            const u16* __restrict__ Vt, u16* __restrict__ ctx) {
  __shared__ __align__(16) u16 Ks[2][KVBLK * HD];    // 2 x 16 KB
  __shared__ __align__(16) u16 Vs[2][HD * KVBLK];    // 2 x 16 KB
  __shared__ __align__(16) u16 Ps[4][32 * KVBLK];    // 4 x 4 KB  => total 80 KB
  const int h = blockIdx.y;
  const int kvh = h / GQA;
  const int qt = (int)(gridDim.x - 1) - (int)blockIdx.x;   // heaviest-first
  const int wave = threadIdx.x >> 6, lane = threadIdx.x & 63;
  const int l15 = lane & 15, l4 = lane >> 4;
  const int l7 = lane & 7, l8 = lane >> 3;
  const int qrow0 = qt * QBLK + wave * 32;

  // Q fragments: rows qrow0 + m2*16 + l15, d chunks c*32 + l4*8 (pre-scaled Q)
  bf16x8 qf[2][4];
#pragma unroll
  for (int m2 = 0; m2 < 2; ++m2)
#pragma unroll
    for (int c = 0; c < 4; ++c)
      qf[m2][c] = *(const bf16x8*)(Q + (size_t)(qrow0 + m2 * 16 + l15) * HID + h * HD + c * 32 + l4 * 8);

  float m_run[2][4], l_run[2][4];
#pragma unroll
  for (int m2 = 0; m2 < 2; ++m2)
#pragma unroll
    for (int r = 0; r < 4; ++r) { m_run[m2][r] = -1e30f; l_run[m2][r] = 0.f; }
  f32x4 oacc[2][8] = {};

  const int nt = 2 * qt + 2;

#define STAGE_KV(KT, BUF)                                                          \
  do {                                                                             \
    const int key0_ = (KT) * KVBLK;                                                \
    _Pragma("unroll")                                                              \
    for (int i = 0; i < 4; ++i) {                                                  \
      int krow = wave * 16 + i * 4 + l4;                                           \
      int kchunk = l15 ^ (krow & 7);                                               \
      async16(&Ks[BUF][(wave * 16 + i * 4) * HD],                                  \
              Kb + (size_t)(key0_ + krow) * (NKVH * HD) + kvh * HD + kchunk * 8);  \
    }                                                                              \
    _Pragma("unroll")                                                              \
    for (int i = 0; i < 4; ++i) {                                                  \
      int vrow = wave * 32 + i * 8 + l8;                                           \
      int vchunk = l7 ^ (vrow & 7);                                                \
      async16(&Vs[BUF][(wave * 32 + i * 8) * KVBLK],                               \
              Vt + (size_t)(kvh * HD + vrow) * S_LEN + key0_ + vchunk * 8);        \
    }                                                                              \
  } while (0)

  STAGE_KV(0, 0);
  __syncthreads();
  int cur = 0;

  for (int kt = 0; kt < nt; ++kt) {
    if (kt + 1 < nt) STAGE_KV(kt + 1, cur ^ 1);   // prefetch flies under compute
    const int key0 = kt * KVBLK;

    // S = Q(32xD) x K^T(Dx64): sa[m2][n], K frag shared across m2
    f32x4 sa[2][4] = {};
#pragma unroll
    for (int n = 0; n < 4; ++n)
#pragma unroll
      for (int c = 0; c < 4; ++c) {
        int krow = n * 16 + l15;
        bf16x8 kf = *(const bf16x8*)(&Ks[cur][krow * HD + (((c * 4 + l4) ^ (krow & 7)) * 8)]);
        sa[0][n] = __builtin_amdgcn_mfma_f32_16x16x32_bf16(qf[0][c], kf, sa[0][n], 0, 0, 0);
        sa[1][n] = __builtin_amdgcn_mfma_f32_16x16x32_bf16(qf[1][c], kf, sa[1][n], 0, 0, 0);
      }

    const bool domask = (key0 + KVBLK) > qt * QBLK;   // tile overlaps diagonal
#pragma unroll
    for (int m2 = 0; m2 < 2; ++m2) {
      if (domask) {
#pragma unroll
        for (int n = 0; n < 4; ++n)
#pragma unroll
          for (int r = 0; r < 4; ++r)
            if (key0 + n * 16 + l15 > qrow0 + m2 * 16 + l4 * 4 + r) sa[m2][n][r] = -1e30f;
      }
      float mnew[4], corr[4];
#pragma unroll
      for (int r = 0; r < 4; ++r) {
        float v = fmaxf(fmaxf(sa[m2][0][r], sa[m2][1][r]), fmaxf(sa[m2][2][r], sa[m2][3][r]));
#pragma unroll
        for (int off = 1; off < 16; off <<= 1) v = fmaxf(v, __shfl_xor(v, off));
        mnew[r] = fmaxf(m_run[m2][r], v);
        corr[r] = __expf(m_run[m2][r] - mnew[r]);
        m_run[m2][r] = mnew[r];
      }
      float pr[4][4];
#pragma unroll
      for (int n = 0; n < 4; ++n)
#pragma unroll
        for (int r = 0; r < 4; ++r) pr[n][r] = __expf(sa[m2][n][r] - mnew[r]);
#pragma unroll
      for (int r = 0; r < 4; ++r) {
        float sum = pr[0][r] + pr[1][r] + pr[2][r] + pr[3][r];
#pragma unroll
        for (int off = 1; off < 16; off <<= 1) sum += __shfl_xor(sum, off);
        l_run[m2][r] = l_run[m2][r] * corr[r] + sum;
      }
#pragma unroll
      for (int f = 0; f < 8; ++f)
#pragma unroll
        for (int r = 0; r < 4; ++r) oacc[m2][f][r] *= corr[r];
      // P -> per-wave swizzled LDS slice (C-layout -> A-layout)
#pragma unroll
      for (int n = 0; n < 4; ++n)
#pragma unroll
        for (int r = 0; r < 4; ++r) {
          int prow = m2 * 16 + l4 * 4 + r;
          int col = n * 16 + l15;
          Ps[wave][prow * KVBLK + (((col >> 3) ^ (prow & 7)) * 8) + (col & 7)] = f2bf(pr[n][r]);
        }
    }
    // wave-synchronous handoff: drain all lanes' ds_writes, pin ordering
    asm volatile("s_waitcnt lgkmcnt(0)" ::: "memory");
    __builtin_amdgcn_sched_barrier(0);

    // O += P(32x64) x V(64xD): V frag shared across m2
#pragma unroll
    for (int c2 = 0; c2 < 2; ++c2) {
      bf16x8 pa[2];
#pragma unroll
      for (int m2 = 0; m2 < 2; ++m2) {
        int prow = m2 * 16 + l15;
        pa[m2] = *(const bf16x8*)(&Ps[wave][prow * KVBLK + (((c2 * 4 + l4) ^ (prow & 7)) * 8)]);
      }
#pragma unroll
      for (int f = 0; f < 8; ++f) {
        int vrow = f * 16 + l15;
        bf16x8 vf = *(const bf16x8*)(&Vs[cur][vrow * KVBLK + (((c2 * 4 + l4) ^ (vrow & 7)) * 8)]);
        oacc[0][f] = __builtin_amdgcn_mfma_f32_16x16x32_bf16(pa[0], vf, oacc[0][f], 0, 0, 0);
        oacc[1][f] = __builtin_amdgcn_mfma_f32_16x16x32_bf16(pa[1], vf, oacc[1][f], 0, 0, 0);
      }
    }
    __syncthreads();   // staging of next tile complete + everyone done with cur
    cur ^= 1;
  }

#pragma unroll
  for (int m2 = 0; m2 < 2; ++m2)
#pragma unroll
    for (int f = 0; f < 8; ++f)
#pragma unroll
      for (int r = 0; r < 4; ++r) {
        float val = oacc[m2][f][r] / l_run[m2][r];
        int row = qrow0 + m2 * 16 + l4 * 4 + r;
        ctx[(size_t)row * HID + h * HD + f * 16 + l15] = f2bf(val);
      }
#undef STAGE_KV
}

extern "C" void kernel_launch(void* const* d_in, const int* in_sizes, int n_in,
                              void* d_out, int out_size, void* d_ws, size_t ws_size,
                              hipStream_t stream) {
  (void)in_sizes; (void)n_in; (void)out_size; (void)ws_size;
  const int* positions = (const int*)d_in[0];
  const float* hs = (const float*)d_in[1];
  const float* Wqkv = (const float*)d_in[2];
  const float* Wo = (const float*)d_in[3];
  const float* wqk = (const float*)d_in[4];
  float* out = (float*)d_out;

  char* ws = (char*)d_ws;
  u16* Wqkv_b = (u16*)ws;                  // [0, 73400320)  dead after GEMM1
  u16* q_b   = (u16*)ws;                   // reuse: [0, 20971520)
  u16* k_b   = (u16*)(ws + 20971520);      // [.., 25165824)
  u16* vt_b  = (u16*)(ws + 25165824);      // [.., 29360128)
  u16* Wo_b  = (u16*)(ws + 73400320);      // [.., 125829120)
  u16* hs_b  = (u16*)(ws + 125829120);     // [.., 146800640)  dead after GEMM1
  u16* ctx_b = hs_b;                       // reuse
  float* qkv = (float*)(ws + 146800640);   // [.., 205520896)

  k_f32_to_bf16<<<2048, 256, 0, stream>>>((const float4*)hs, (uint2*)hs_b, (S_LEN * HID) / 4);
  k_f32_to_bf16<<<2048, 256, 0, stream>>>((const float4*)Wqkv, (uint2*)Wqkv_b, (QKV_COLS * HID) / 4);
  k_f32_to_bf16<<<2048, 256, 0, stream>>>((const float4*)Wo, (uint2*)Wo_b, (HID * HID) / 4);

  k_gemm_bt<<<dim3(QKV_COLS / 128, S_LEN / 128), 256, 0, stream>>>(hs_b, Wqkv_b, qkv, S_LEN, QKV_COLS, HID);

  k_rope_norm<<<(S_LEN * 48) / 4, 256, 0, stream>>>(qkv, positions, wqk, q_b, k_b);
  k_vtrans<<<dim3(S_LEN / 32, NKVH), 256, 0, stream>>>(qkv, vt_b);

  k_attn<<<dim3(S_LEN / QBLK, NHEAD), 256, 0, stream>>>(q_b, k_b, vt_b, ctx_b);

  k_gemm_bt<<<dim3(HID / 128, S_LEN / 128), 256, 0, stream>>>(ctx_b, Wo_b, out, S_LEN, HID, HID);
}

// Round 4
// 683.240 us; speedup vs baseline: 1.7651x; 1.1177x over previous
//
#include <hip/hip_runtime.h>

typedef unsigned short u16;
typedef __bf16 bf16x8 __attribute__((ext_vector_type(8)));
typedef float f32x4 __attribute__((ext_vector_type(4)));

#define S_LEN 2048
#define HID 5120
#define NHEAD 40
#define NKVH 8
#define HD 128
#define QKV_COLS 7168   // (40 + 2*8) * 128
#define GQA 5
#define QBLK 128
#define KVBLK 64

// RNE f32 -> bf16
__device__ __forceinline__ u16 f2bf(float f) {
  unsigned u = __float_as_uint(f);
  u += 0x7FFFu + ((u >> 16) & 1u);
  return (u16)(u >> 16);
}

// async global->LDS, 16B per lane; LDS base must be wave-uniform
__device__ __forceinline__ void async16(void* lds, const void* g) {
  __builtin_amdgcn_global_load_lds(
      (const __attribute__((address_space(1))) unsigned int*)g,
      (__attribute__((address_space(3))) unsigned int*)lds, 16, 0, 0);
}

// ---------- f32 -> bf16 elementwise convert ----------
__global__ void k_f32_to_bf16(const float4* __restrict__ in, uint2* __restrict__ out, int n4) {
  int i = blockIdx.x * blockDim.x + threadIdx.x;
  int stride = gridDim.x * blockDim.x;
  for (; i < n4; i += stride) {
    float4 v = in[i];
    uint2 o;
    o.x = (unsigned)f2bf(v.x) | ((unsigned)f2bf(v.y) << 16);
    o.y = (unsigned)f2bf(v.z) | ((unsigned)f2bf(v.w) << 16);
    out[i] = o;
  }
}

// ---------- 256x256 8-phase GEMM: C[M,N] f32 = A[M,K] bf16 * B[N,K]^T bf16 ----------
// 8 waves (2Mx4N), BK=64, 128 KiB LDS double-buffered, counted vmcnt(4) at
// phases 4/8 only, chunk^(row&7) swizzle (both-sides), setprio around MFMA.
// Requires M%256==0, N%256==0, K%128==0.
__global__ __launch_bounds__(512, 2)
void k_gemm256(const u16* __restrict__ A, const u16* __restrict__ B,
               float* __restrict__ C, int M, int N, int K, int gx) {
  __shared__ __align__(16) u16 As[2][2][128 * 64];   // [buf][half][row*64+col]
  __shared__ __align__(16) u16 Bs[2][2][128 * 64];
  const int tid = threadIdx.x;
  const int wave = tid >> 6, lane = tid & 63;
  const int l15 = lane & 15, l4 = lane >> 4;
  const int wm = wave >> 2, wn = wave & 3;

  // XCD-aware swizzle (grid counts are multiples of 8 here)
  const int nwg = gridDim.x;
  int f = blockIdx.x;
  int swz = (nwg % 8 == 0) ? ((f & 7) * (nwg >> 3) + (f >> 3)) : f;
  const int bx = swz % gx, by = swz / gx;
  const int row0 = by * 256, col0 = bx * 256;

  // staging geometry: thread covers row srow(+64), swizzled chunk
  const int srow = tid >> 3;                         // 0..63
  const int sgch = ((tid & 7) ^ (srow & 7)) * 8;     // global chunk offset (elems)
  // read-side swizzled chunk offsets (elems): chunk = (kk*4 + l4) ^ (row&7)
  const int s7 = l15 & 7;
  const int ch0 = (l4 ^ s7) * 8;
  const int ch1 = ((4 + l4) ^ s7) * 8;

  f32x4 acc[8][4] = {};

#define STG_A(buf, half, kt)                                                        \
  do {                                                                              \
    const size_t k0_ = (size_t)(kt) * 64;                                           \
    async16(&As[buf][half][(wave * 8) * 64],                                        \
            A + (size_t)(row0 + (half) * 128 + srow) * K + k0_ + sgch);             \
    async16(&As[buf][half][(64 + wave * 8) * 64],                                   \
            A + (size_t)(row0 + (half) * 128 + 64 + srow) * K + k0_ + sgch);        \
  } while (0)
#define STG_B(buf, half, kt)                                                        \
  do {                                                                              \
    const size_t k0_ = (size_t)(kt) * 64;                                           \
    async16(&Bs[buf][half][(wave * 8) * 64],                                        \
            B + (size_t)(col0 + (half) * 128 + srow) * K + k0_ + sgch);             \
    async16(&Bs[buf][half][(64 + wave * 8) * 64],                                   \
            B + (size_t)(col0 + (half) * 128 + 64 + srow) * K + k0_ + sgch);        \
  } while (0)

  // phase: ds-read quadrant -> stage issue -> [vmcnt] -> barrier -> lgkmcnt(0)
  //        -> setprio(1) -> 16 MFMA -> setprio(0) -> barrier
#define PH(buf, q, STAGE, VM)                                                       \
  {                                                                                 \
    bf16x8 af[2][2];                                                                \
    _Pragma("unroll") for (int e = 0; e < 2; ++e) {                                 \
      const u16* pa = &As[buf][wm][((2 * (q) + e) * 16 + l15) * 64];                \
      af[e][0] = *(const bf16x8*)(pa + ch0);                                        \
      af[e][1] = *(const bf16x8*)(pa + ch1);                                        \
    }                                                                               \
    if ((q) == 0) {                                                                 \
      _Pragma("unroll") for (int n = 0; n < 4; ++n) {                               \
        const u16* pb = &Bs[buf][wn >> 1][((wn & 1) * 64 + n * 16 + l15) * 64];     \
        bfr[n][0] = *(const bf16x8*)(pb + ch0);                                     \
        bfr[n][1] = *(const bf16x8*)(pb + ch1);                                     \
      }                                                                             \
    }                                                                               \
    STAGE;                                                                          \
    VM;                                                                             \
    __builtin_amdgcn_s_barrier();                                                   \
    asm volatile("s_waitcnt lgkmcnt(0)" ::: "memory");                              \
    __builtin_amdgcn_sched_barrier(0);                                              \
    __builtin_amdgcn_s_setprio(1);                                                  \
    _Pragma("unroll") for (int e = 0; e < 2; ++e)                                   \
      _Pragma("unroll") for (int n = 0; n < 4; ++n) {                               \
        acc[2 * (q) + e][n] = __builtin_amdgcn_mfma_f32_16x16x32_bf16(              \
            af[e][0], bfr[n][0], acc[2 * (q) + e][n], 0, 0, 0);                     \
        acc[2 * (q) + e][n] = __builtin_amdgcn_mfma_f32_16x16x32_bf16(              \
            af[e][1], bfr[n][1], acc[2 * (q) + e][n], 0, 0, 0);                     \
      }                                                                             \
    __builtin_amdgcn_s_setprio(0);                                                  \
    __builtin_amdgcn_s_barrier();                                                   \
  }
#define VM4 asm volatile("s_waitcnt vmcnt(4)" ::: "memory")
#define VMNONE

  const int nkt = K >> 6;       // K-tiles of 64 (even; >= 2)
  const int niter = nkt >> 1;

  // prologue: tile0 (A+B) -> buf0, tile1 B -> buf1; drain to last 2 half-tiles
  STG_A(0, 0, 0); STG_A(0, 1, 0);
  STG_B(0, 0, 0); STG_B(0, 1, 0);
  STG_B(1, 0, 1); STG_B(1, 1, 1);
  VM4;
  __builtin_amdgcn_s_barrier();

  for (int i = 0; i < niter; ++i) {
    const int t1 = 2 * i + 1, t2 = 2 * i + 2, t3 = 2 * i + 3;
    bf16x8 bfr[4][2];
    // tile 2i from buf0; stage A(t1)->buf1, B(t2)->buf0
    PH(0, 0, STG_A(1, 0, t1), VMNONE)
    PH(0, 1, STG_A(1, 1, t1), VMNONE)
    PH(0, 2, if (t2 < nkt) STG_B(0, 0, t2), VMNONE)
    PH(0, 3, if (t2 < nkt) STG_B(0, 1, t2), VM4)
    // tile 2i+1 from buf1; stage A(t2)->buf0, B(t3)->buf1
    PH(1, 0, if (t2 < nkt) STG_A(0, 0, t2), VMNONE)
    PH(1, 1, if (t2 < nkt) STG_A(0, 1, t2), VMNONE)
    PH(1, 2, if (t3 < nkt) STG_B(1, 0, t3), VMNONE)
    PH(1, 3, if (t3 < nkt) STG_B(1, 1, t3), VM4)
  }

#pragma unroll
  for (int m = 0; m < 8; ++m)
#pragma unroll
    for (int n = 0; n < 4; ++n)
#pragma unroll
      for (int r = 0; r < 4; ++r) {
        int row = row0 + wm * 128 + m * 16 + l4 * 4 + r;
        int col = col0 + wn * 64 + n * 16 + l15;
        C[(size_t)row * N + col] = acc[m][n][r];
      }
#undef STG_A
#undef STG_B
#undef PH
#undef VM4
#undef VMNONE
}

// ---------- RoPE (neox) + per-head RMSNorm ----------
__global__ void k_rope_norm(const float* __restrict__ qkv, const int* __restrict__ pos,
                            const float* __restrict__ wqk,
                            u16* __restrict__ qo, u16* __restrict__ ko) {
  const int wid = (blockIdx.x * blockDim.x + threadIdx.x) >> 6;
  const int lane = threadIdx.x & 63;
  const int s = wid / 48;
  const int r = wid - s * 48;
  const float* src;
  u16* dst;
  const bool isq = (r < NHEAD);
  if (isq) {
    src = qkv + (size_t)s * QKV_COLS + r * HD;
    dst = qo + (size_t)s * (NHEAD * HD) + r * HD;
  } else {
    int kv = r - NHEAD;
    src = qkv + (size_t)s * QKV_COLS + HID + kv * HD;
    dst = ko + (size_t)s * (NKVH * HD) + kv * HD;
  }
  float x1 = src[lane], x2 = src[lane + 64];
  float p = (float)pos[s];
  float ang = p * exp2f(-(float)lane * (18.931568569324174f / 64.0f));
  float sn, cs;
  sincosf(ang, &sn, &cs);
  float y1 = x1 * cs - x2 * sn;
  float y2 = x2 * cs + x1 * sn;
  float ss = y1 * y1 + y2 * y2;
#pragma unroll
  for (int off = 32; off > 0; off >>= 1) ss += __shfl_xor(ss, off);
  float rms = rsqrtf(ss * (1.0f / 128.0f) + 1e-5f);
  float sc = isq ? 0.08838834764831843f : 1.0f;
  dst[lane] = f2bf(y1 * rms * wqk[lane] * sc);
  dst[lane + 64] = f2bf(y2 * rms * wqk[lane + 64] * sc);
}

// ---------- V: [s][6144 + kvh*128 + d] f32 -> Vt[kvh][d][s] bf16 ----------
__global__ void k_vtrans(const float* __restrict__ qkv, u16* __restrict__ vt) {
  __shared__ float t[32][129];
  const int s0 = blockIdx.x * 32;
  const int kv = blockIdx.y;
  for (int i = threadIdx.x; i < 32 * 128; i += 256) {
    int sr = i >> 7, d = i & 127;
    t[sr][d] = qkv[(size_t)(s0 + sr) * QKV_COLS + (HID + NKVH * HD) + kv * HD + d];
  }
  __syncthreads();
  for (int i = threadIdx.x; i < 32 * 128; i += 256) {
    int d = i >> 5, sc = i & 31;
    vt[((size_t)kv * HD + d) * S_LEN + s0 + sc] = f2bf(t[sc][d]);
  }
}

// ---------- causal GQA flash attention (round-3, verified) ----------
__global__ __launch_bounds__(256, 2)
void k_attn(const u16* __restrict__ Q, const u16* __restrict__ Kb,
            const u16* __restrict__ Vt, u16* __restrict__ ctx) {
  __shared__ __align__(16) u16 Ks[2][KVBLK * HD];
  __shared__ __align__(16) u16 Vs[2][HD * KVBLK];
  __shared__ __align__(16) u16 Ps[4][32 * KVBLK];
  const int h = blockIdx.y;
  const int kvh = h / GQA;
  const int qt = (int)(gridDim.x - 1) - (int)blockIdx.x;
  const int wave = threadIdx.x >> 6, lane = threadIdx.x & 63;
  const int l15 = lane & 15, l4 = lane >> 4;
  const int l7 = lane & 7, l8 = lane >> 3;
  const int qrow0 = qt * QBLK + wave * 32;

  bf16x8 qf[2][4];
#pragma unroll
  for (int m2 = 0; m2 < 2; ++m2)
#pragma unroll
    for (int c = 0; c < 4; ++c)
      qf[m2][c] = *(const bf16x8*)(Q + (size_t)(qrow0 + m2 * 16 + l15) * HID + h * HD + c * 32 + l4 * 8);

  float m_run[2][4], l_run[2][4];
#pragma unroll
  for (int m2 = 0; m2 < 2; ++m2)
#pragma unroll
    for (int r = 0; r < 4; ++r) { m_run[m2][r] = -1e30f; l_run[m2][r] = 0.f; }
  f32x4 oacc[2][8] = {};

  const int nt = 2 * qt + 2;

#define STAGE_KV(KT, BUF)                                                          \
  do {                                                                             \
    const int key0_ = (KT) * KVBLK;                                                \
    _Pragma("unroll")                                                              \
    for (int i = 0; i < 4; ++i) {                                                  \
      int krow = wave * 16 + i * 4 + l4;                                           \
      int kchunk = l15 ^ (krow & 7);                                               \
      async16(&Ks[BUF][(wave * 16 + i * 4) * HD],                                  \
              Kb + (size_t)(key0_ + krow) * (NKVH * HD) + kvh * HD + kchunk * 8);  \
    }                                                                              \
    _Pragma("unroll")                                                              \
    for (int i = 0; i < 4; ++i) {                                                  \
      int vrow = wave * 32 + i * 8 + l8;                                           \
      int vchunk = l7 ^ (vrow & 7);                                                \
      async16(&Vs[BUF][(wave * 32 + i * 8) * KVBLK],                               \
              Vt + (size_t)(kvh * HD + vrow) * S_LEN + key0_ + vchunk * 8);        \
    }                                                                              \
  } while (0)

  STAGE_KV(0, 0);
  __syncthreads();
  int cur = 0;

  for (int kt = 0; kt < nt; ++kt) {
    if (kt + 1 < nt) STAGE_KV(kt + 1, cur ^ 1);
    const int key0 = kt * KVBLK;

    f32x4 sa[2][4] = {};
#pragma unroll
    for (int n = 0; n < 4; ++n)
#pragma unroll
      for (int c = 0; c < 4; ++c) {
        int krow = n * 16 + l15;
        bf16x8 kf = *(const bf16x8*)(&Ks[cur][krow * HD + (((c * 4 + l4) ^ (krow & 7)) * 8)]);
        sa[0][n] = __builtin_amdgcn_mfma_f32_16x16x32_bf16(qf[0][c], kf, sa[0][n], 0, 0, 0);
        sa[1][n] = __builtin_amdgcn_mfma_f32_16x16x32_bf16(qf[1][c], kf, sa[1][n], 0, 0, 0);
      }

    const bool domask = (key0 + KVBLK) > qt * QBLK;
#pragma unroll
    for (int m2 = 0; m2 < 2; ++m2) {
      if (domask) {
#pragma unroll
        for (int n = 0; n < 4; ++n)
#pragma unroll
          for (int r = 0; r < 4; ++r)
            if (key0 + n * 16 + l15 > qrow0 + m2 * 16 + l4 * 4 + r) sa[m2][n][r] = -1e30f;
      }
      float mnew[4], corr[4];
#pragma unroll
      for (int r = 0; r < 4; ++r) {
        float v = fmaxf(fmaxf(sa[m2][0][r], sa[m2][1][r]), fmaxf(sa[m2][2][r], sa[m2][3][r]));
#pragma unroll
        for (int off = 1; off < 16; off <<= 1) v = fmaxf(v, __shfl_xor(v, off));
        mnew[r] = fmaxf(m_run[m2][r], v);
        corr[r] = __expf(m_run[m2][r] - mnew[r]);
        m_run[m2][r] = mnew[r];
      }
      float pr[4][4];
#pragma unroll
      for (int n = 0; n < 4; ++n)
#pragma unroll
        for (int r = 0; r < 4; ++r) pr[n][r] = __expf(sa[m2][n][r] - mnew[r]);
#pragma unroll
      for (int r = 0; r < 4; ++r) {
        float sum = pr[0][r] + pr[1][r] + pr[2][r] + pr[3][r];
#pragma unroll
        for (int off = 1; off < 16; off <<= 1) sum += __shfl_xor(sum, off);
        l_run[m2][r] = l_run[m2][r] * corr[r] + sum;
      }
#pragma unroll
      for (int f = 0; f < 8; ++f)
#pragma unroll
        for (int r = 0; r < 4; ++r) oacc[m2][f][r] *= corr[r];
#pragma unroll
      for (int n = 0; n < 4; ++n)
#pragma unroll
        for (int r = 0; r < 4; ++r) {
          int prow = m2 * 16 + l4 * 4 + r;
          int col = n * 16 + l15;
          Ps[wave][prow * KVBLK + (((col >> 3) ^ (prow & 7)) * 8) + (col & 7)] = f2bf(pr[n][r]);
        }
    }
    asm volatile("s_waitcnt lgkmcnt(0)" ::: "memory");
    __builtin_amdgcn_sched_barrier(0);

#pragma unroll
    for (int c2 = 0; c2 < 2; ++c2) {
      bf16x8 pa[2];
#pragma unroll
      for (int m2 = 0; m2 < 2; ++m2) {
        int prow = m2 * 16 + l15;
        pa[m2] = *(const bf16x8*)(&Ps[wave][prow * KVBLK + (((c2 * 4 + l4) ^ (prow & 7)) * 8)]);
      }
#pragma unroll
      for (int f = 0; f < 8; ++f) {
        int vrow = f * 16 + l15;
        bf16x8 vf = *(const bf16x8*)(&Vs[cur][vrow * KVBLK + (((c2 * 4 + l4) ^ (vrow & 7)) * 8)]);
        oacc[0][f] = __builtin_amdgcn_mfma_f32_16x16x32_bf16(pa[0], vf, oacc[0][f], 0, 0, 0);
        oacc[1][f] = __builtin_amdgcn_mfma_f32_16x16x32_bf16(pa[1], vf, oacc[1][f], 0, 0, 0);
      }
    }
    __syncthreads();
    cur ^= 1;
  }

#pragma unroll
  for (int m2 = 0; m2 < 2; ++m2)
#pragma unroll
    for (int f = 0; f < 8; ++f)
#pragma unroll
      for (int r = 0; r < 4; ++r) {
        float val = oacc[m2][f][r] / l_run[m2][r];
        int row = qrow0 + m2 * 16 + l4 * 4 + r;
        ctx[(size_t)row * HID + h * HD + f * 16 + l15] = f2bf(val);
      }
#undef STAGE_KV
}

extern "C" void kernel_launch(void* const* d_in, const int* in_sizes, int n_in,
                              void* d_out, int out_size, void* d_ws, size_t ws_size,
                              hipStream_t stream) {
  (void)in_sizes; (void)n_in; (void)out_size; (void)ws_size;
  const int* positions = (const int*)d_in[0];
  const float* hs = (const float*)d_in[1];
  const float* Wqkv = (const float*)d_in[2];
  const float* Wo = (const float*)d_in[3];
  const float* wqk = (const float*)d_in[4];
  float* out = (float*)d_out;

  char* ws = (char*)d_ws;
  u16* Wqkv_b = (u16*)ws;                  // [0, 73400320)  dead after GEMM1
  u16* q_b   = (u16*)ws;                   // reuse: [0, 20971520)
  u16* k_b   = (u16*)(ws + 20971520);      // [.., 25165824)
  u16* vt_b  = (u16*)(ws + 25165824);      // [.., 29360128)
  u16* Wo_b  = (u16*)(ws + 73400320);      // [.., 125829120)
  u16* hs_b  = (u16*)(ws + 125829120);     // [.., 146800640)  dead after GEMM1
  u16* ctx_b = hs_b;                       // reuse
  float* qkv = (float*)(ws + 146800640);   // [.., 205520896)

  k_f32_to_bf16<<<2048, 256, 0, stream>>>((const float4*)hs, (uint2*)hs_b, (S_LEN * HID) / 4);
  k_f32_to_bf16<<<2048, 256, 0, stream>>>((const float4*)Wqkv, (uint2*)Wqkv_b, (QKV_COLS * HID) / 4);
  k_f32_to_bf16<<<2048, 256, 0, stream>>>((const float4*)Wo, (uint2*)Wo_b, (HID * HID) / 4);

  k_gemm256<<<dim3((QKV_COLS / 256) * (S_LEN / 256)), 512, 0, stream>>>(
      hs_b, Wqkv_b, qkv, S_LEN, QKV_COLS, HID, QKV_COLS / 256);

  k_rope_norm<<<(S_LEN * 48) / 4, 256, 0, stream>>>(qkv, positions, wqk, q_b, k_b);
  k_vtrans<<<dim3(S_LEN / 32, NKVH), 256, 0, stream>>>(qkv, vt_b);

  k_attn<<<dim3(S_LEN / QBLK, NHEAD), 256, 0, stream>>>(q_b, k_b, vt_b, ctx_b);

  k_gemm256<<<dim3((HID / 256) * (S_LEN / 256)), 512, 0, stream>>>(
      ctx_b, Wo_b, out, S_LEN, HID, HID, HID / 256);
}

// Round 5
// 642.051 us; speedup vs baseline: 1.8784x; 1.0642x over previous
//
#include <hip/hip_runtime.h>

typedef unsigned short u16;
typedef __bf16 bf16x8 __attribute__((ext_vector_type(8)));
typedef float f32x4 __attribute__((ext_vector_type(4)));
typedef unsigned u32x4 __attribute__((ext_vector_type(4)));

#define S_LEN 2048
#define HID 5120
#define NHEAD 40
#define NKVH 8
#define HD 128
#define QKV_COLS 7168   // (40 + 2*8) * 128
#define GQA 5
#define QBLK 128
#define KVBLK 64

// RNE f32 -> bf16
__device__ __forceinline__ u16 f2bf(float f) {
  unsigned u = __float_as_uint(f);
  u += 0x7FFFu + ((u >> 16) & 1u);
  return (u16)(u >> 16);
}

// async global->LDS, 16B per lane; LDS base must be wave-uniform
__device__ __forceinline__ void async16(void* lds, const void* g) {
  __builtin_amdgcn_global_load_lds(
      (const __attribute__((address_space(1))) unsigned int*)g,
      (__attribute__((address_space(3))) unsigned int*)lds, 16, 0, 0);
}

// ---------- f32 -> bf16 elementwise convert ----------
__global__ void k_f32_to_bf16(const float4* __restrict__ in, uint2* __restrict__ out, int n4) {
  int i = blockIdx.x * blockDim.x + threadIdx.x;
  int stride = gridDim.x * blockDim.x;
  for (; i < n4; i += stride) {
    float4 v = in[i];
    uint2 o;
    o.x = (unsigned)f2bf(v.x) | ((unsigned)f2bf(v.y) << 16);
    o.y = (unsigned)f2bf(v.z) | ((unsigned)f2bf(v.w) << 16);
    out[i] = o;
  }
}

// ---------- 256x256 8-phase GEMM (round-4, verified) ----------
__global__ __launch_bounds__(512, 2)
void k_gemm256(const u16* __restrict__ A, const u16* __restrict__ B,
               float* __restrict__ C, int M, int N, int K, int gx) {
  __shared__ __align__(16) u16 As[2][2][128 * 64];
  __shared__ __align__(16) u16 Bs[2][2][128 * 64];
  const int tid = threadIdx.x;
  const int wave = tid >> 6, lane = tid & 63;
  const int l15 = lane & 15, l4 = lane >> 4;
  const int wm = wave >> 2, wn = wave & 3;

  const int nwg = gridDim.x;
  int f = blockIdx.x;
  int swz = (nwg % 8 == 0) ? ((f & 7) * (nwg >> 3) + (f >> 3)) : f;
  const int bx = swz % gx, by = swz / gx;
  const int row0 = by * 256, col0 = bx * 256;

  const int srow = tid >> 3;
  const int sgch = ((tid & 7) ^ (srow & 7)) * 8;
  const int s7 = l15 & 7;
  const int ch0 = (l4 ^ s7) * 8;
  const int ch1 = ((4 + l4) ^ s7) * 8;

  f32x4 acc[8][4] = {};

#define STG_A(buf, half, kt)                                                        \
  do {                                                                              \
    const size_t k0_ = (size_t)(kt) * 64;                                           \
    async16(&As[buf][half][(wave * 8) * 64],                                        \
            A + (size_t)(row0 + (half) * 128 + srow) * K + k0_ + sgch);             \
    async16(&As[buf][half][(64 + wave * 8) * 64],                                   \
            A + (size_t)(row0 + (half) * 128 + 64 + srow) * K + k0_ + sgch);        \
  } while (0)
#define STG_B(buf, half, kt)                                                        \
  do {                                                                              \
    const size_t k0_ = (size_t)(kt) * 64;                                           \
    async16(&Bs[buf][half][(wave * 8) * 64],                                        \
            B + (size_t)(col0 + (half) * 128 + srow) * K + k0_ + sgch);             \
    async16(&Bs[buf][half][(64 + wave * 8) * 64],                                   \
            B + (size_t)(col0 + (half) * 128 + 64 + srow) * K + k0_ + sgch);        \
  } while (0)

#define PH(buf, q, STAGE, VM)                                                       \
  {                                                                                 \
    bf16x8 af[2][2];                                                                \
    _Pragma("unroll") for (int e = 0; e < 2; ++e) {                                 \
      const u16* pa = &As[buf][wm][((2 * (q) + e) * 16 + l15) * 64];                \
      af[e][0] = *(const bf16x8*)(pa + ch0);                                        \
      af[e][1] = *(const bf16x8*)(pa + ch1);                                        \
    }                                                                               \
    if ((q) == 0) {                                                                 \
      _Pragma("unroll") for (int n = 0; n < 4; ++n) {                               \
        const u16* pb = &Bs[buf][wn >> 1][((wn & 1) * 64 + n * 16 + l15) * 64];     \
        bfr[n][0] = *(const bf16x8*)(pb + ch0);                                     \
        bfr[n][1] = *(const bf16x8*)(pb + ch1);                                     \
      }                                                                             \
    }                                                                               \
    STAGE;                                                                          \
    VM;                                                                             \
    __builtin_amdgcn_s_barrier();                                                   \
    asm volatile("s_waitcnt lgkmcnt(0)" ::: "memory");                              \
    __builtin_amdgcn_sched_barrier(0);                                              \
    __builtin_amdgcn_s_setprio(1);                                                  \
    _Pragma("unroll") for (int e = 0; e < 2; ++e)                                   \
      _Pragma("unroll") for (int n = 0; n < 4; ++n) {                               \
        acc[2 * (q) + e][n] = __builtin_amdgcn_mfma_f32_16x16x32_bf16(              \
            af[e][0], bfr[n][0], acc[2 * (q) + e][n], 0, 0, 0);                     \
        acc[2 * (q) + e][n] = __builtin_amdgcn_mfma_f32_16x16x32_bf16(              \
            af[e][1], bfr[n][1], acc[2 * (q) + e][n], 0, 0, 0);                     \
      }                                                                             \
    __builtin_amdgcn_s_setprio(0);                                                  \
    __builtin_amdgcn_s_barrier();                                                   \
  }
#define VM4 asm volatile("s_waitcnt vmcnt(4)" ::: "memory")
#define VMNONE

  const int nkt = K >> 6;
  const int niter = nkt >> 1;

  STG_A(0, 0, 0); STG_A(0, 1, 0);
  STG_B(0, 0, 0); STG_B(0, 1, 0);
  STG_B(1, 0, 1); STG_B(1, 1, 1);
  VM4;
  __builtin_amdgcn_s_barrier();

  for (int i = 0; i < niter; ++i) {
    const int t1 = 2 * i + 1, t2 = 2 * i + 2, t3 = 2 * i + 3;
    bf16x8 bfr[4][2];
    PH(0, 0, STG_A(1, 0, t1), VMNONE)
    PH(0, 1, STG_A(1, 1, t1), VMNONE)
    PH(0, 2, if (t2 < nkt) STG_B(0, 0, t2), VMNONE)
    PH(0, 3, if (t2 < nkt) STG_B(0, 1, t2), VM4)
    PH(1, 0, if (t2 < nkt) STG_A(0, 0, t2), VMNONE)
    PH(1, 1, if (t2 < nkt) STG_A(0, 1, t2), VMNONE)
    PH(1, 2, if (t3 < nkt) STG_B(1, 0, t3), VMNONE)
    PH(1, 3, if (t3 < nkt) STG_B(1, 1, t3), VM4)
  }

#pragma unroll
  for (int m = 0; m < 8; ++m)
#pragma unroll
    for (int n = 0; n < 4; ++n)
#pragma unroll
      for (int r = 0; r < 4; ++r) {
        int row = row0 + wm * 128 + m * 16 + l4 * 4 + r;
        int col = col0 + wn * 64 + n * 16 + l15;
        C[(size_t)row * N + col] = acc[m][n][r];
      }
#undef STG_A
#undef STG_B
#undef PH
#undef VM4
#undef VMNONE
}

// ---------- RoPE (neox) + per-head RMSNorm ----------
__global__ void k_rope_norm(const float* __restrict__ qkv, const int* __restrict__ pos,
                            const float* __restrict__ wqk,
                            u16* __restrict__ qo, u16* __restrict__ ko) {
  const int wid = (blockIdx.x * blockDim.x + threadIdx.x) >> 6;
  const int lane = threadIdx.x & 63;
  const int s = wid / 48;
  const int r = wid - s * 48;
  const float* src;
  u16* dst;
  const bool isq = (r < NHEAD);
  if (isq) {
    src = qkv + (size_t)s * QKV_COLS + r * HD;
    dst = qo + (size_t)s * (NHEAD * HD) + r * HD;
  } else {
    int kv = r - NHEAD;
    src = qkv + (size_t)s * QKV_COLS + HID + kv * HD;
    dst = ko + (size_t)s * (NKVH * HD) + kv * HD;
  }
  float x1 = src[lane], x2 = src[lane + 64];
  float p = (float)pos[s];
  float ang = p * exp2f(-(float)lane * (18.931568569324174f / 64.0f));
  float sn, cs;
  sincosf(ang, &sn, &cs);
  float y1 = x1 * cs - x2 * sn;
  float y2 = x2 * cs + x1 * sn;
  float ss = y1 * y1 + y2 * y2;
#pragma unroll
  for (int off = 32; off > 0; off >>= 1) ss += __shfl_xor(ss, off);
  float rms = rsqrtf(ss * (1.0f / 128.0f) + 1e-5f);
  float sc = isq ? 0.08838834764831843f : 1.0f;
  dst[lane] = f2bf(y1 * rms * wqk[lane] * sc);
  dst[lane + 64] = f2bf(y2 * rms * wqk[lane + 64] * sc);
}

// ---------- V: [s][6144 + kvh*128 + d] f32 -> Vt[kvh][d][s] bf16 ----------
__global__ void k_vtrans(const float* __restrict__ qkv, u16* __restrict__ vt) {
  __shared__ float t[32][129];
  const int s0 = blockIdx.x * 32;
  const int kv = blockIdx.y;
  for (int i = threadIdx.x; i < 32 * 128; i += 256) {
    int sr = i >> 7, d = i & 127;
    t[sr][d] = qkv[(size_t)(s0 + sr) * QKV_COLS + (HID + NKVH * HD) + kv * HD + d];
  }
  __syncthreads();
  for (int i = threadIdx.x; i < 32 * 128; i += 256) {
    int d = i >> 5, sc = i & 31;
    vt[((size_t)kv * HD + d) * S_LEN + s0 + sc] = f2bf(t[sc][d]);
  }
}

// ---------- causal GQA flash attention, swapped-QK^T + in-register P ----------
// grid (16 qt, 40 h), 4 waves, QBLK=128 (wave: 32 q-rows), KVBLK=64.
// LDS 64KB (K/V dbuf only) -> 2 blocks/CU. Counted vmcnt(8), raw s_barrier.
// QK^T computed as mfma(K,Q): S[key=n*16+l4*4+r][q=m2*16+l15]; softmax is
// in-lane(16) + shfl_xor(16,32); P redistributed to PV A-frags in-register.
__global__ __launch_bounds__(256, 2)
void k_attn(const u16* __restrict__ Q, const u16* __restrict__ Kb,
            const u16* __restrict__ Vt, u16* __restrict__ ctx) {
  __shared__ __align__(16) u16 Ks[2][KVBLK * HD];    // 2 x 16 KB
  __shared__ __align__(16) u16 Vs[2][HD * KVBLK];    // 2 x 16 KB  => 64 KB total
  const int h = blockIdx.y;
  const int kvh = h / GQA;
  const int qt = (int)(gridDim.x - 1) - (int)blockIdx.x;   // heaviest-first
  const int lane = threadIdx.x & 63;
  const int wave = threadIdx.x >> 6;
  const int l15 = lane & 15, l4 = lane >> 4;
  const int l7 = lane & 7, l8 = lane >> 3;
  const int qrow0 = qt * QBLK + wave * 32;

  // Q as B-fragments (rows m2*16+l15, chunk c*32+l4*8); Q pre-scaled by D^-0.5
  bf16x8 qf[2][4];
#pragma unroll
  for (int c = 0; c < 4; ++c)
#pragma unroll
    for (int m2 = 0; m2 < 2; ++m2)
      qf[m2][c] = *(const bf16x8*)(Q + (size_t)(qrow0 + m2 * 16 + l15) * HID + h * HD + c * 32 + l4 * 8);

  float m_run[2] = {-1e30f, -1e30f};
  float l_run[2] = {0.f, 0.f};
  f32x4 oacc[2][8] = {};

  const int nt = 2 * qt + 2;   // always even

#define STAGE_KV(KT, BUF)                                                          \
  do {                                                                             \
    const int key0_ = (KT) * KVBLK;                                                \
    _Pragma("unroll")                                                              \
    for (int i = 0; i < 4; ++i) {                                                  \
      int krow = wave * 16 + i * 4 + l4;                                           \
      int kchunk = l15 ^ (krow & 7);                                               \
      async16(&Ks[BUF][(wave * 16 + i * 4) * HD],                                  \
              Kb + (size_t)(key0_ + krow) * (NKVH * HD) + kvh * HD + kchunk * 8);  \
    }                                                                              \
    _Pragma("unroll")                                                              \
    for (int i = 0; i < 4; ++i) {                                                  \
      int vrow = wave * 32 + i * 8 + l8;                                           \
      int vchunk = l7 ^ (vrow & 7);                                                \
      async16(&Vs[BUF][(wave * 32 + i * 8) * KVBLK],                               \
              Vt + (size_t)(kvh * HD + vrow) * S_LEN + key0_ + vchunk * 8);        \
    }                                                                              \
  } while (0)

#define VM8 asm volatile("s_waitcnt vmcnt(8)" ::: "memory")
#define VM0 asm volatile("s_waitcnt vmcnt(0)" ::: "memory")
#define BAR __builtin_amdgcn_s_barrier(); __builtin_amdgcn_sched_barrier(0)

#define COMPUTE(BUF, KT)                                                           \
  {                                                                                \
    const int key0 = (KT) * KVBLK;                                                 \
    f32x4 sa[2][4] = {};                                                           \
    _Pragma("unroll")                                                              \
    for (int n = 0; n < 4; ++n) {                                                  \
      const int krow = n * 16 + l15;                                               \
      const u16* kp = &Ks[BUF][krow * HD];                                         \
      _Pragma("unroll")                                                            \
      for (int c = 0; c < 4; ++c) {                                                \
        bf16x8 kf = *(const bf16x8*)(kp + ((c * 4 + l4) ^ (krow & 7)) * 8);        \
        sa[0][n] = __builtin_amdgcn_mfma_f32_16x16x32_bf16(kf, qf[0][c], sa[0][n], 0, 0, 0); \
        sa[1][n] = __builtin_amdgcn_mfma_f32_16x16x32_bf16(kf, qf[1][c], sa[1][n], 0, 0, 0); \
      }                                                                            \
    }                                                                              \
    const bool domask = (key0 + KVBLK) > qt * QBLK;                                \
    bf16x8 pa[2][2];                                                               \
    _Pragma("unroll")                                                              \
    for (int m2 = 0; m2 < 2; ++m2) {                                               \
      const int qrow = qrow0 + m2 * 16 + l15;                                      \
      if (domask) {                                                                \
        _Pragma("unroll")                                                          \
        for (int n = 0; n < 4; ++n)                                                \
          _Pragma("unroll")                                                        \
          for (int r = 0; r < 4; ++r)                                              \
            if (key0 + n * 16 + l4 * 4 + r > qrow) sa[m2][n][r] = -1e30f;          \
      }                                                                            \
      float mx = sa[m2][0][0];                                                     \
      _Pragma("unroll")                                                            \
      for (int n = 0; n < 4; ++n)                                                  \
        _Pragma("unroll")                                                          \
        for (int r = 0; r < 4; ++r) mx = fmaxf(mx, sa[m2][n][r]);                  \
      mx = fmaxf(mx, __shfl_xor(mx, 16));                                          \
      mx = fmaxf(mx, __shfl_xor(mx, 32));                                          \
      const float mnew = fmaxf(m_run[m2], mx);                                     \
      const float corr = __expf(m_run[m2] - mnew);                                 \
      m_run[m2] = mnew;                                                            \
      float p[4][4];                                                               \
      float sum = 0.f;                                                             \
      _Pragma("unroll")                                                            \
      for (int n = 0; n < 4; ++n)                                                  \
        _Pragma("unroll")                                                          \
        for (int r = 0; r < 4; ++r) { p[n][r] = __expf(sa[m2][n][r] - mnew); sum += p[n][r]; } \
      sum += __shfl_xor(sum, 16);                                                  \
      sum += __shfl_xor(sum, 32);                                                  \
      l_run[m2] = l_run[m2] * corr + sum;                                          \
      /* rescale oacc: corr is per q=l15; oacc rows are q=l4*4+r -> shfl */        \
      _Pragma("unroll")                                                            \
      for (int r = 0; r < 4; ++r) {                                                \
        float cc = __shfl(corr, (lane & 48) + ((lane >> 4) << 2) + r);             \
        _Pragma("unroll")                                                          \
        for (int f2 = 0; f2 < 8; ++f2) oacc[m2][f2][r] *= cc;                      \
      }                                                                            \
      /* pack P to bf16 pairs: pkk[n][hi] = keys (n*16+l4*4+2hi, +1) */            \
      unsigned pkk[4][2];                                                          \
      _Pragma("unroll")                                                            \
      for (int n = 0; n < 4; ++n)                                                  \
        _Pragma("unroll")                                                          \
        for (int hi = 0; hi < 2; ++hi)                                             \
          pkk[n][hi] = (unsigned)f2bf(p[n][2 * hi]) | ((unsigned)f2bf(p[n][2 * hi + 1]) << 16); \
      /* redistribute to A-frag: lane needs keys c2*32 + l4*8 + 0..7 */            \
      const int s0l = ((lane >> 4) & 1) * 32 + (lane & 15);                        \
      const bool hiSel = (lane & 32) != 0;                                         \
      _Pragma("unroll")                                                            \
      for (int c2 = 0; c2 < 2; ++c2) {                                             \
        unsigned ox[4];                                                            \
        _Pragma("unroll")                                                          \
        for (int i = 0; i < 4; ++i) {                                              \
          int srcl = s0l + ((i >> 1) << 4);                                        \
          unsigned lo = (unsigned)__shfl((int)pkk[2 * c2][i & 1], srcl);           \
          unsigned hi2 = (unsigned)__shfl((int)pkk[2 * c2 + 1][i & 1], srcl);      \
          ox[i] = hiSel ? hi2 : lo;                                                \
        }                                                                          \
        u32x4 tmp = {ox[0], ox[1], ox[2], ox[3]};                                  \
        pa[m2][c2] = __builtin_bit_cast(bf16x8, tmp);                              \
      }                                                                            \
    }                                                                              \
    /* O += P(32x64) x V(64x128) */                                                \
    _Pragma("unroll")                                                              \
    for (int f2 = 0; f2 < 8; ++f2) {                                               \
      const int vrow = f2 * 16 + l15;                                              \
      const u16* vp = &Vs[BUF][vrow * KVBLK];                                      \
      _Pragma("unroll")                                                            \
      for (int c2 = 0; c2 < 2; ++c2) {                                             \
        bf16x8 vf = *(const bf16x8*)(vp + ((c2 * 4 + l4) ^ (vrow & 7)) * 8);       \
        oacc[0][f2] = __builtin_amdgcn_mfma_f32_16x16x32_bf16(pa[0][c2], vf, oacc[0][f2], 0, 0, 0); \
        oacc[1][f2] = __builtin_amdgcn_mfma_f32_16x16x32_bf16(pa[1][c2], vf, oacc[1][f2], 0, 0, 0); \
      }                                                                            \
    }                                                                              \
  }

  // prologue: two tiles in flight
  STAGE_KV(0, 0);
  STAGE_KV(1, 1);

  int t = 0;
  for (; t + 2 < nt; t += 2) {
    VM8; BAR;                       // stage(t) landed everywhere
    COMPUTE(0, t)
    BAR;                            // all waves done reading buf0
    STAGE_KV(t + 2, 0);
    VM8; BAR;                       // stage(t+1) landed
    COMPUTE(1, t + 1)
    BAR;                            // all waves done reading buf1
    if (t + 3 < nt) STAGE_KV(t + 3, 1);
  }
  // peel last two tiles (no further staging)
  VM8; BAR;
  COMPUTE(0, nt - 2)
  VM0; BAR;
  COMPUTE(1, nt - 1)

  // epilogue: l_run is per q=l15; oacc rows are q=l4*4+r -> shfl
#pragma unroll
  for (int m2 = 0; m2 < 2; ++m2)
#pragma unroll
    for (int r = 0; r < 4; ++r) {
      float li = 1.0f / __shfl(l_run[m2], (lane & 48) + ((lane >> 4) << 2) + r);
      int row = qrow0 + m2 * 16 + l4 * 4 + r;
#pragma unroll
      for (int f2 = 0; f2 < 8; ++f2)
        ctx[(size_t)row * HID + h * HD + f2 * 16 + l15] = f2bf(oacc[m2][f2][r] * li);
    }
#undef STAGE_KV
#undef VM8
#undef VM0
#undef BAR
#undef COMPUTE
}

extern "C" void kernel_launch(void* const* d_in, const int* in_sizes, int n_in,
                              void* d_out, int out_size, void* d_ws, size_t ws_size,
                              hipStream_t stream) {
  (void)in_sizes; (void)n_in; (void)out_size; (void)ws_size;
  const int* positions = (const int*)d_in[0];
  const float* hs = (const float*)d_in[1];
  const float* Wqkv = (const float*)d_in[2];
  const float* Wo = (const float*)d_in[3];
  const float* wqk = (const float*)d_in[4];
  float* out = (float*)d_out;

  char* ws = (char*)d_ws;
  u16* Wqkv_b = (u16*)ws;                  // [0, 73400320)  dead after GEMM1
  u16* q_b   = (u16*)ws;                   // reuse: [0, 20971520)
  u16* k_b   = (u16*)(ws + 20971520);      // [.., 25165824)
  u16* vt_b  = (u16*)(ws + 25165824);      // [.., 29360128)
  u16* Wo_b  = (u16*)(ws + 73400320);      // [.., 125829120)
  u16* hs_b  = (u16*)(ws + 125829120);     // [.., 146800640)  dead after GEMM1
  u16* ctx_b = hs_b;                       // reuse
  float* qkv = (float*)(ws + 146800640);   // [.., 205520896)

  k_f32_to_bf16<<<2048, 256, 0, stream>>>((const float4*)hs, (uint2*)hs_b, (S_LEN * HID) / 4);
  k_f32_to_bf16<<<2048, 256, 0, stream>>>((const float4*)Wqkv, (uint2*)Wqkv_b, (QKV_COLS * HID) / 4);
  k_f32_to_bf16<<<2048, 256, 0, stream>>>((const float4*)Wo, (uint2*)Wo_b, (HID * HID) / 4);

  k_gemm256<<<dim3((QKV_COLS / 256) * (S_LEN / 256)), 512, 0, stream>>>(
      hs_b, Wqkv_b, qkv, S_LEN, QKV_COLS, HID, QKV_COLS / 256);

  k_rope_norm<<<(S_LEN * 48) / 4, 256, 0, stream>>>(qkv, positions, wqk, q_b, k_b);
  k_vtrans<<<dim3(S_LEN / 32, NKVH), 256, 0, stream>>>(qkv, vt_b);

  k_attn<<<dim3(S_LEN / QBLK, NHEAD), 256, 0, stream>>>(q_b, k_b, vt_b, ctx_b);

  k_gemm256<<<dim3((HID / 256) * (S_LEN / 256)), 512, 0, stream>>>(
      ctx_b, Wo_b, out, S_LEN, HID, HID, HID / 256);
}

// Round 6
// 618.810 us; speedup vs baseline: 1.9489x; 1.0376x over previous
//
#include <hip/hip_runtime.h>

typedef unsigned short u16;
typedef __bf16 bf16x8 __attribute__((ext_vector_type(8)));
typedef float f32x4 __attribute__((ext_vector_type(4)));
typedef unsigned u32x4 __attribute__((ext_vector_type(4)));

#define S_LEN 2048
#define HID 5120
#define NHEAD 40
#define NKVH 8
#define HD 128
#define QKV_COLS 7168   // (40 + 2*8) * 128
#define GQA 5
#define QBLK 128
#define KVBLK 64

// RNE f32 -> bf16
__device__ __forceinline__ u16 f2bf(float f) {
  unsigned u = __float_as_uint(f);
  u += 0x7FFFu + ((u >> 16) & 1u);
  return (u16)(u >> 16);
}

// async global->LDS, 16B per lane; LDS base must be wave-uniform
__device__ __forceinline__ void async16(void* lds, const void* g) {
  __builtin_amdgcn_global_load_lds(
      (const __attribute__((address_space(1))) unsigned int*)g,
      (__attribute__((address_space(3))) unsigned int*)lds, 16, 0, 0);
}

// ---------- f32 -> bf16 elementwise convert ----------
__global__ void k_f32_to_bf16(const float4* __restrict__ in, uint2* __restrict__ out, int n4) {
  int i = blockIdx.x * blockDim.x + threadIdx.x;
  int stride = gridDim.x * blockDim.x;
  for (; i < n4; i += stride) {
    float4 v = in[i];
    uint2 o;
    o.x = (unsigned)f2bf(v.x) | ((unsigned)f2bf(v.y) << 16);
    o.y = (unsigned)f2bf(v.z) | ((unsigned)f2bf(v.w) << 16);
    out[i] = o;
  }
}

// ---------- 256x256 GEMM, 8 phases/pair, ONE barrier per phase ----------
// Phase: [ds_read][vmcnt?][s_barrier][lgkm0+schedbar][stage(post-bar)][prio MFMA].
// Safety: phase-p reads complete at own lgkm0 (pre next bar) => post-bar stage
// at p+1 cannot overwrite live data; counted vmcnt(2) pre-bar at ph3/ph7 lands
// exactly the half-tiles the next phase group reads (2-load tail in flight).
__global__ __launch_bounds__(512, 2)
void k_gemm256(const u16* __restrict__ A, const u16* __restrict__ B,
               float* __restrict__ C, int M, int N, int K, int gx) {
  __shared__ __align__(16) u16 As[2][2][128 * 64];
  __shared__ __align__(16) u16 Bs[2][2][128 * 64];
  const int tid = threadIdx.x;
  const int wave = tid >> 6, lane = tid & 63;
  const int l15 = lane & 15, l4 = lane >> 4;
  const int wm = wave >> 2, wn = wave & 3;

  const int nwg = gridDim.x;
  int f = blockIdx.x;
  int swz = (nwg % 8 == 0) ? ((f & 7) * (nwg >> 3) + (f >> 3)) : f;
  const int bx = swz % gx, by = swz / gx;
  const int row0 = by * 256, col0 = bx * 256;

  const int srow = tid >> 3;
  const int sgch = ((tid & 7) ^ (srow & 7)) * 8;
  const int s7 = l15 & 7;
  const int ch0 = (l4 ^ s7) * 8;
  const int ch1 = ((4 + l4) ^ s7) * 8;

  f32x4 acc[8][4] = {};

#define STG_A(buf, half, kt)                                                        \
  do {                                                                              \
    const size_t k0_ = (size_t)(kt) * 64;                                           \
    async16(&As[buf][half][(wave * 8) * 64],                                        \
            A + (size_t)(row0 + (half) * 128 + srow) * K + k0_ + sgch);             \
    async16(&As[buf][half][(64 + wave * 8) * 64],                                   \
            A + (size_t)(row0 + (half) * 128 + 64 + srow) * K + k0_ + sgch);        \
  } while (0)
#define STG_B(buf, half, kt)                                                        \
  do {                                                                              \
    const size_t k0_ = (size_t)(kt) * 64;                                           \
    async16(&Bs[buf][half][(wave * 8) * 64],                                        \
            B + (size_t)(col0 + (half) * 128 + srow) * K + k0_ + sgch);             \
    async16(&Bs[buf][half][(64 + wave * 8) * 64],                                   \
            B + (size_t)(col0 + (half) * 128 + 64 + srow) * K + k0_ + sgch);        \
  } while (0)

#define PH(buf, q, STAGE, VM)                                                       \
  {                                                                                 \
    bf16x8 af[2][2];                                                                \
    _Pragma("unroll") for (int e = 0; e < 2; ++e) {                                 \
      const u16* pa = &As[buf][wm][((2 * (q) + e) * 16 + l15) * 64];                \
      af[e][0] = *(const bf16x8*)(pa + ch0);                                        \
      af[e][1] = *(const bf16x8*)(pa + ch1);                                        \
    }                                                                               \
    if ((q) == 0) {                                                                 \
      _Pragma("unroll") for (int n = 0; n < 4; ++n) {                               \
        const u16* pb = &Bs[buf][wn >> 1][((wn & 1) * 64 + n * 16 + l15) * 64];     \
        bfr[n][0] = *(const bf16x8*)(pb + ch0);                                     \
        bfr[n][1] = *(const bf16x8*)(pb + ch1);                                     \
      }                                                                             \
    }                                                                               \
    VM;                                                                             \
    __builtin_amdgcn_s_barrier();                                                   \
    asm volatile("s_waitcnt lgkmcnt(0)" ::: "memory");                              \
    __builtin_amdgcn_sched_barrier(0);                                              \
    STAGE;                                                                          \
    __builtin_amdgcn_s_setprio(1);                                                  \
    _Pragma("unroll") for (int e = 0; e < 2; ++e)                                   \
      _Pragma("unroll") for (int n = 0; n < 4; ++n) {                               \
        acc[2 * (q) + e][n] = __builtin_amdgcn_mfma_f32_16x16x32_bf16(              \
            af[e][0], bfr[n][0], acc[2 * (q) + e][n], 0, 0, 0);                     \
        acc[2 * (q) + e][n] = __builtin_amdgcn_mfma_f32_16x16x32_bf16(              \
            af[e][1], bfr[n][1], acc[2 * (q) + e][n], 0, 0, 0);                     \
      }                                                                             \
    __builtin_amdgcn_s_setprio(0);                                                  \
  }
#define VM2 asm volatile("s_waitcnt vmcnt(2)" ::: "memory")
#define VM0 asm volatile("s_waitcnt vmcnt(0)" ::: "memory")
#define VMNONE

  const int nkt = K >> 6;       // K-tiles of 64 (even, >= 2)
  const int niter = nkt >> 1;

  // prologue: tile0 A+B -> buf0, tile1 B -> buf1; 12 loads, drain to last 4
  STG_A(0, 0, 0); STG_A(0, 1, 0);
  STG_B(0, 0, 0); STG_B(0, 1, 0);
  STG_B(1, 0, 1); STG_B(1, 1, 1);
  asm volatile("s_waitcnt vmcnt(4)" ::: "memory");
  __builtin_amdgcn_s_barrier();

  // main loop (all stages unguarded: i+1 < niter => t3 <= nkt-1)
  for (int i = 0; i + 1 < niter; ++i) {
    const int t1 = 2 * i + 1, t2 = 2 * i + 2, t3 = 2 * i + 3;
    bf16x8 bfr[4][2];
    PH(0, 0, STG_A(1, 0, t1), VMNONE)
    PH(0, 1, STG_A(1, 1, t1), VMNONE)
    PH(0, 2, STG_B(0, 0, t2), VMNONE)
    PH(0, 3, STG_B(0, 1, t2), VM2)
    PH(1, 0, STG_A(0, 0, t2), VMNONE)
    PH(1, 1, STG_A(0, 1, t2), VMNONE)
    PH(1, 2, STG_B(1, 0, t3), VMNONE)
    PH(1, 3, STG_B(1, 1, t3), VM2)
  }
  // peeled final pair: only A(t1) still to stage; drain fully before buf1 group
  {
    const int t1 = nkt - 1;
    bf16x8 bfr[4][2];
    PH(0, 0, STG_A(1, 0, t1), VMNONE)
    PH(0, 1, STG_A(1, 1, t1), VMNONE)
    PH(0, 2, ((void)0), VMNONE)
    PH(0, 3, ((void)0), VM0)
    PH(1, 0, ((void)0), VMNONE)
    PH(1, 1, ((void)0), VMNONE)
    PH(1, 2, ((void)0), VMNONE)
    PH(1, 3, ((void)0), VMNONE)
  }

#pragma unroll
  for (int m = 0; m < 8; ++m)
#pragma unroll
    for (int n = 0; n < 4; ++n)
#pragma unroll
      for (int r = 0; r < 4; ++r) {
        int row = row0 + wm * 128 + m * 16 + l4 * 4 + r;
        int col = col0 + wn * 64 + n * 16 + l15;
        C[(size_t)row * N + col] = acc[m][n][r];
      }
#undef STG_A
#undef STG_B
#undef PH
#undef VM2
#undef VM0
#undef VMNONE
}

// ---------- RoPE (neox) + per-head RMSNorm ----------
__global__ void k_rope_norm(const float* __restrict__ qkv, const int* __restrict__ pos,
                            const float* __restrict__ wqk,
                            u16* __restrict__ qo, u16* __restrict__ ko) {
  const int wid = (blockIdx.x * blockDim.x + threadIdx.x) >> 6;
  const int lane = threadIdx.x & 63;
  const int s = wid / 48;
  const int r = wid - s * 48;
  const float* src;
  u16* dst;
  const bool isq = (r < NHEAD);
  if (isq) {
    src = qkv + (size_t)s * QKV_COLS + r * HD;
    dst = qo + (size_t)s * (NHEAD * HD) + r * HD;
  } else {
    int kv = r - NHEAD;
    src = qkv + (size_t)s * QKV_COLS + HID + kv * HD;
    dst = ko + (size_t)s * (NKVH * HD) + kv * HD;
  }
  float x1 = src[lane], x2 = src[lane + 64];
  float p = (float)pos[s];
  float ang = p * exp2f(-(float)lane * (18.931568569324174f / 64.0f));
  float sn, cs;
  sincosf(ang, &sn, &cs);
  float y1 = x1 * cs - x2 * sn;
  float y2 = x2 * cs + x1 * sn;
  float ss = y1 * y1 + y2 * y2;
#pragma unroll
  for (int off = 32; off > 0; off >>= 1) ss += __shfl_xor(ss, off);
  float rms = rsqrtf(ss * (1.0f / 128.0f) + 1e-5f);
  float sc = isq ? 0.08838834764831843f : 1.0f;
  dst[lane] = f2bf(y1 * rms * wqk[lane] * sc);
  dst[lane + 64] = f2bf(y2 * rms * wqk[lane + 64] * sc);
}

// ---------- V: [s][6144 + kvh*128 + d] f32 -> Vt[kvh][d][s] bf16 ----------
__global__ void k_vtrans(const float* __restrict__ qkv, u16* __restrict__ vt) {
  __shared__ float t[32][129];
  const int s0 = blockIdx.x * 32;
  const int kv = blockIdx.y;
  for (int i = threadIdx.x; i < 32 * 128; i += 256) {
    int sr = i >> 7, d = i & 127;
    t[sr][d] = qkv[(size_t)(s0 + sr) * QKV_COLS + (HID + NKVH * HD) + kv * HD + d];
  }
  __syncthreads();
  for (int i = threadIdx.x; i < 32 * 128; i += 256) {
    int d = i >> 5, sc = i & 31;
    vt[((size_t)kv * HD + d) * S_LEN + s0 + sc] = f2bf(t[sc][d]);
  }
}

// ---------- causal GQA flash attention (round-5, verified) ----------
__global__ __launch_bounds__(256, 2)
void k_attn(const u16* __restrict__ Q, const u16* __restrict__ Kb,
            const u16* __restrict__ Vt, u16* __restrict__ ctx) {
  __shared__ __align__(16) u16 Ks[2][KVBLK * HD];
  __shared__ __align__(16) u16 Vs[2][HD * KVBLK];
  const int h = blockIdx.y;
  const int kvh = h / GQA;
  const int qt = (int)(gridDim.x - 1) - (int)blockIdx.x;
  const int lane = threadIdx.x & 63;
  const int wave = threadIdx.x >> 6;
  const int l15 = lane & 15, l4 = lane >> 4;
  const int l7 = lane & 7, l8 = lane >> 3;
  const int qrow0 = qt * QBLK + wave * 32;

  bf16x8 qf[2][4];
#pragma unroll
  for (int c = 0; c < 4; ++c)
#pragma unroll
    for (int m2 = 0; m2 < 2; ++m2)
      qf[m2][c] = *(const bf16x8*)(Q + (size_t)(qrow0 + m2 * 16 + l15) * HID + h * HD + c * 32 + l4 * 8);

  float m_run[2] = {-1e30f, -1e30f};
  float l_run[2] = {0.f, 0.f};
  f32x4 oacc[2][8] = {};

  const int nt = 2 * qt + 2;

#define STAGE_KV(KT, BUF)                                                          \
  do {                                                                             \
    const int key0_ = (KT) * KVBLK;                                                \
    _Pragma("unroll")                                                              \
    for (int i = 0; i < 4; ++i) {                                                  \
      int krow = wave * 16 + i * 4 + l4;                                           \
      int kchunk = l15 ^ (krow & 7);                                               \
      async16(&Ks[BUF][(wave * 16 + i * 4) * HD],                                  \
              Kb + (size_t)(key0_ + krow) * (NKVH * HD) + kvh * HD + kchunk * 8);  \
    }                                                                              \
    _Pragma("unroll")                                                              \
    for (int i = 0; i < 4; ++i) {                                                  \
      int vrow = wave * 32 + i * 8 + l8;                                           \
      int vchunk = l7 ^ (vrow & 7);                                                \
      async16(&Vs[BUF][(wave * 32 + i * 8) * KVBLK],                               \
              Vt + (size_t)(kvh * HD + vrow) * S_LEN + key0_ + vchunk * 8);        \
    }                                                                              \
  } while (0)

#define VM8 asm volatile("s_waitcnt vmcnt(8)" ::: "memory")
#define VM0 asm volatile("s_waitcnt vmcnt(0)" ::: "memory")
#define BAR __builtin_amdgcn_s_barrier(); __builtin_amdgcn_sched_barrier(0)

#define COMPUTE(BUF, KT)                                                           \
  {                                                                                \
    const int key0 = (KT) * KVBLK;                                                 \
    f32x4 sa[2][4] = {};                                                           \
    _Pragma("unroll")                                                              \
    for (int n = 0; n < 4; ++n) {                                                  \
      const int krow = n * 16 + l15;                                               \
      const u16* kp = &Ks[BUF][krow * HD];                                         \
      _Pragma("unroll")                                                            \
      for (int c = 0; c < 4; ++c) {                                                \
        bf16x8 kf = *(const bf16x8*)(kp + ((c * 4 + l4) ^ (krow & 7)) * 8);        \
        sa[0][n] = __builtin_amdgcn_mfma_f32_16x16x32_bf16(kf, qf[0][c], sa[0][n], 0, 0, 0); \
        sa[1][n] = __builtin_amdgcn_mfma_f32_16x16x32_bf16(kf, qf[1][c], sa[1][n], 0, 0, 0); \
      }                                                                            \
    }                                                                              \
    const bool domask = (key0 + KVBLK) > qt * QBLK;                                \
    bf16x8 pa[2][2];                                                               \
    _Pragma("unroll")                                                              \
    for (int m2 = 0; m2 < 2; ++m2) {                                               \
      const int qrow = qrow0 + m2 * 16 + l15;                                      \
      if (domask) {                                                                \
        _Pragma("unroll")                                                          \
        for (int n = 0; n < 4; ++n)                                                \
          _Pragma("unroll")                                                        \
          for (int r = 0; r < 4; ++r)                                              \
            if (key0 + n * 16 + l4 * 4 + r > qrow) sa[m2][n][r] = -1e30f;          \
      }                                                                            \
      float mx = sa[m2][0][0];                                                     \
      _Pragma("unroll")                                                            \
      for (int n = 0; n < 4; ++n)                                                  \
        _Pragma("unroll")                                                          \
        for (int r = 0; r < 4; ++r) mx = fmaxf(mx, sa[m2][n][r]);                  \
      mx = fmaxf(mx, __shfl_xor(mx, 16));                                          \
      mx = fmaxf(mx, __shfl_xor(mx, 32));                                          \
      const float mnew = fmaxf(m_run[m2], mx);                                     \
      const float corr = __expf(m_run[m2] - mnew);                                 \
      m_run[m2] = mnew;                                                            \
      float p[4][4];                                                               \
      float sum = 0.f;                                                             \
      _Pragma("unroll")                                                            \
      for (int n = 0; n < 4; ++n)                                                  \
        _Pragma("unroll")                                                          \
        for (int r = 0; r < 4; ++r) { p[n][r] = __expf(sa[m2][n][r] - mnew); sum += p[n][r]; } \
      sum += __shfl_xor(sum, 16);                                                  \
      sum += __shfl_xor(sum, 32);                                                  \
      l_run[m2] = l_run[m2] * corr + sum;                                          \
      _Pragma("unroll")                                                            \
      for (int r = 0; r < 4; ++r) {                                                \
        float cc = __shfl(corr, (lane & 48) + ((lane >> 4) << 2) + r);             \
        _Pragma("unroll")                                                          \
        for (int f2 = 0; f2 < 8; ++f2) oacc[m2][f2][r] *= cc;                      \
      }                                                                            \
      unsigned pkk[4][2];                                                          \
      _Pragma("unroll")                                                            \
      for (int n = 0; n < 4; ++n)                                                  \
        _Pragma("unroll")                                                          \
        for (int hi = 0; hi < 2; ++hi)                                             \
          pkk[n][hi] = (unsigned)f2bf(p[n][2 * hi]) | ((unsigned)f2bf(p[n][2 * hi + 1]) << 16); \
      const int s0l = ((lane >> 4) & 1) * 32 + (lane & 15);                        \
      const bool hiSel = (lane & 32) != 0;                                         \
      _Pragma("unroll")                                                            \
      for (int c2 = 0; c2 < 2; ++c2) {                                             \
        unsigned ox[4];                                                            \
        _Pragma("unroll")                                                          \
        for (int i = 0; i < 4; ++i) {                                              \
          int srcl = s0l + ((i >> 1) << 4);                                        \
          unsigned lo = (unsigned)__shfl((int)pkk[2 * c2][i & 1], srcl);           \
          unsigned hi2 = (unsigned)__shfl((int)pkk[2 * c2 + 1][i & 1], srcl);      \
          ox[i] = hiSel ? hi2 : lo;                                                \
        }                                                                          \
        u32x4 tmp = {ox[0], ox[1], ox[2], ox[3]};                                  \
        pa[m2][c2] = __builtin_bit_cast(bf16x8, tmp);                              \
      }                                                                            \
    }                                                                              \
    _Pragma("unroll")                                                              \
    for (int f2 = 0; f2 < 8; ++f2) {                                               \
      const int vrow = f2 * 16 + l15;                                              \
      const u16* vp = &Vs[BUF][vrow * KVBLK];                                      \
      _Pragma("unroll")                                                            \
      for (int c2 = 0; c2 < 2; ++c2) {                                             \
        bf16x8 vf = *(const bf16x8*)(vp + ((c2 * 4 + l4) ^ (vrow & 7)) * 8);       \
        oacc[0][f2] = __builtin_amdgcn_mfma_f32_16x16x32_bf16(pa[0][c2], vf, oacc[0][f2], 0, 0, 0); \
        oacc[1][f2] = __builtin_amdgcn_mfma_f32_16x16x32_bf16(pa[1][c2], vf, oacc[1][f2], 0, 0, 0); \
      }                                                                            \
    }                                                                              \
  }

  STAGE_KV(0, 0);
  STAGE_KV(1, 1);

  int t = 0;
  for (; t + 2 < nt; t += 2) {
    VM8; BAR;
    COMPUTE(0, t)
    BAR;
    STAGE_KV(t + 2, 0);
    VM8; BAR;
    COMPUTE(1, t + 1)
    BAR;
    if (t + 3 < nt) STAGE_KV(t + 3, 1);
  }
  VM8; BAR;
  COMPUTE(0, nt - 2)
  VM0; BAR;
  COMPUTE(1, nt - 1)

#pragma unroll
  for (int m2 = 0; m2 < 2; ++m2)
#pragma unroll
    for (int r = 0; r < 4; ++r) {
      float li = 1.0f / __shfl(l_run[m2], (lane & 48) + ((lane >> 4) << 2) + r);
      int row = qrow0 + m2 * 16 + l4 * 4 + r;
#pragma unroll
      for (int f2 = 0; f2 < 8; ++f2)
        ctx[(size_t)row * HID + h * HD + f2 * 16 + l15] = f2bf(oacc[m2][f2][r] * li);
    }
#undef STAGE_KV
#undef VM8
#undef VM0
#undef BAR
#undef COMPUTE
}

extern "C" void kernel_launch(void* const* d_in, const int* in_sizes, int n_in,
                              void* d_out, int out_size, void* d_ws, size_t ws_size,
                              hipStream_t stream) {
  (void)in_sizes; (void)n_in; (void)out_size; (void)ws_size;
  const int* positions = (const int*)d_in[0];
  const float* hs = (const float*)d_in[1];
  const float* Wqkv = (const float*)d_in[2];
  const float* Wo = (const float*)d_in[3];
  const float* wqk = (const float*)d_in[4];
  float* out = (float*)d_out;

  char* ws = (char*)d_ws;
  u16* Wqkv_b = (u16*)ws;                  // [0, 73400320)  dead after GEMM1
  u16* q_b   = (u16*)ws;                   // reuse: [0, 20971520)
  u16* k_b   = (u16*)(ws + 20971520);      // [.., 25165824)
  u16* vt_b  = (u16*)(ws + 25165824);      // [.., 29360128)
  u16* Wo_b  = (u16*)(ws + 73400320);      // [.., 125829120)
  u16* hs_b  = (u16*)(ws + 125829120);     // [.., 146800640)  dead after GEMM1
  u16* ctx_b = hs_b;                       // reuse
  float* qkv = (float*)(ws + 146800640);   // [.., 205520896)

  k_f32_to_bf16<<<2048, 256, 0, stream>>>((const float4*)hs, (uint2*)hs_b, (S_LEN * HID) / 4);
  k_f32_to_bf16<<<2048, 256, 0, stream>>>((const float4*)Wqkv, (uint2*)Wqkv_b, (QKV_COLS * HID) / 4);
  k_f32_to_bf16<<<2048, 256, 0, stream>>>((const float4*)Wo, (uint2*)Wo_b, (HID * HID) / 4);

  k_gemm256<<<dim3((QKV_COLS / 256) * (S_LEN / 256)), 512, 0, stream>>>(
      hs_b, Wqkv_b, qkv, S_LEN, QKV_COLS, HID, QKV_COLS / 256);

  k_rope_norm<<<(S_LEN * 48) / 4, 256, 0, stream>>>(qkv, positions, wqk, q_b, k_b);
  k_vtrans<<<dim3(S_LEN / 32, NKVH), 256, 0, stream>>>(qkv, vt_b);

  k_attn<<<dim3(S_LEN / QBLK, NHEAD), 256, 0, stream>>>(q_b, k_b, vt_b, ctx_b);

  k_gemm256<<<dim3((HID / 256) * (S_LEN / 256)), 512, 0, stream>>>(
      ctx_b, Wo_b, out, S_LEN, HID, HID, HID / 256);
}

// Round 7
// 539.382 us; speedup vs baseline: 2.2359x; 1.1473x over previous
//
#include <hip/hip_runtime.h>

typedef unsigned short u16;
typedef __bf16 bf16x8 __attribute__((ext_vector_type(8)));
typedef float f32x4 __attribute__((ext_vector_type(4)));
typedef unsigned u32x4 __attribute__((ext_vector_type(4)));

#define S_LEN 2048
#define HID 5120
#define NHEAD 40
#define NKVH 8
#define HD 128
#define QKV_COLS 7168   // (40 + 2*8) * 128
#define GQA 5
#define QBLK 128
#define KVBLK 64
#define NQT (S_LEN / QBLK)        // 16
#define NITEMS (NQT * NHEAD)      // 640

// RNE f32 -> bf16
__device__ __forceinline__ u16 f2bf(float f) {
  unsigned u = __float_as_uint(f);
  u += 0x7FFFu + ((u >> 16) & 1u);
  return (u16)(u >> 16);
}

// async global->LDS, 16B per lane; LDS base must be wave-uniform
__device__ __forceinline__ void async16(void* lds, const void* g) {
  __builtin_amdgcn_global_load_lds(
      (const __attribute__((address_space(1))) unsigned int*)g,
      (__attribute__((address_space(3))) unsigned int*)lds, 16, 0, 0);
}

// ---------- f32 -> bf16 elementwise convert ----------
__global__ void k_f32_to_bf16(const float4* __restrict__ in, uint2* __restrict__ out, int n4) {
  int i = blockIdx.x * blockDim.x + threadIdx.x;
  int stride = gridDim.x * blockDim.x;
  for (; i < n4; i += stride) {
    float4 v = in[i];
    uint2 o;
    o.x = (unsigned)f2bf(v.x) | ((unsigned)f2bf(v.y) << 16);
    o.y = (unsigned)f2bf(v.z) | ((unsigned)f2bf(v.w) << 16);
    out[i] = o;
  }
}

// ---------- 256x256 GEMM, 8 phases/pair, ONE barrier per phase (round-6) ----------
__global__ __launch_bounds__(512, 2)
void k_gemm256(const u16* __restrict__ A, const u16* __restrict__ B,
               float* __restrict__ C, int M, int N, int K, int gx) {
  __shared__ __align__(16) u16 As[2][2][128 * 64];
  __shared__ __align__(16) u16 Bs[2][2][128 * 64];
  const int tid = threadIdx.x;
  const int wave = tid >> 6, lane = tid & 63;
  const int l15 = lane & 15, l4 = lane >> 4;
  const int wm = wave >> 2, wn = wave & 3;

  const int nwg = gridDim.x;
  int f = blockIdx.x;
  int swz = (nwg % 8 == 0) ? ((f & 7) * (nwg >> 3) + (f >> 3)) : f;
  const int bx = swz % gx, by = swz / gx;
  const int row0 = by * 256, col0 = bx * 256;

  const int srow = tid >> 3;
  const int sgch = ((tid & 7) ^ (srow & 7)) * 8;
  const int s7 = l15 & 7;
  const int ch0 = (l4 ^ s7) * 8;
  const int ch1 = ((4 + l4) ^ s7) * 8;

  f32x4 acc[8][4] = {};

#define STG_A(buf, half, kt)                                                        \
  do {                                                                              \
    const size_t k0_ = (size_t)(kt) * 64;                                           \
    async16(&As[buf][half][(wave * 8) * 64],                                        \
            A + (size_t)(row0 + (half) * 128 + srow) * K + k0_ + sgch);             \
    async16(&As[buf][half][(64 + wave * 8) * 64],                                   \
            A + (size_t)(row0 + (half) * 128 + 64 + srow) * K + k0_ + sgch);        \
  } while (0)
#define STG_B(buf, half, kt)                                                        \
  do {                                                                              \
    const size_t k0_ = (size_t)(kt) * 64;                                           \
    async16(&Bs[buf][half][(wave * 8) * 64],                                        \
            B + (size_t)(col0 + (half) * 128 + srow) * K + k0_ + sgch);             \
    async16(&Bs[buf][half][(64 + wave * 8) * 64],                                   \
            B + (size_t)(col0 + (half) * 128 + 64 + srow) * K + k0_ + sgch);        \
  } while (0)

#define PH(buf, q, STAGE, VM)                                                       \
  {                                                                                 \
    bf16x8 af[2][2];                                                                \
    _Pragma("unroll") for (int e = 0; e < 2; ++e) {                                 \
      const u16* pa = &As[buf][wm][((2 * (q) + e) * 16 + l15) * 64];                \
      af[e][0] = *(const bf16x8*)(pa + ch0);                                        \
      af[e][1] = *(const bf16x8*)(pa + ch1);                                        \
    }                                                                               \
    if ((q) == 0) {                                                                 \
      _Pragma("unroll") for (int n = 0; n < 4; ++n) {                               \
        const u16* pb = &Bs[buf][wn >> 1][((wn & 1) * 64 + n * 16 + l15) * 64];     \
        bfr[n][0] = *(const bf16x8*)(pb + ch0);                                     \
        bfr[n][1] = *(const bf16x8*)(pb + ch1);                                     \
      }                                                                             \
    }                                                                               \
    VM;                                                                             \
    __builtin_amdgcn_s_barrier();                                                   \
    asm volatile("s_waitcnt lgkmcnt(0)" ::: "memory");                              \
    __builtin_amdgcn_sched_barrier(0);                                              \
    STAGE;                                                                          \
    __builtin_amdgcn_s_setprio(1);                                                  \
    _Pragma("unroll") for (int e = 0; e < 2; ++e)                                   \
      _Pragma("unroll") for (int n = 0; n < 4; ++n) {                               \
        acc[2 * (q) + e][n] = __builtin_amdgcn_mfma_f32_16x16x32_bf16(              \
            af[e][0], bfr[n][0], acc[2 * (q) + e][n], 0, 0, 0);                     \
        acc[2 * (q) + e][n] = __builtin_amdgcn_mfma_f32_16x16x32_bf16(              \
            af[e][1], bfr[n][1], acc[2 * (q) + e][n], 0, 0, 0);                     \
      }                                                                             \
    __builtin_amdgcn_s_setprio(0);                                                  \
  }
#define VM2 asm volatile("s_waitcnt vmcnt(2)" ::: "memory")
#define VM0 asm volatile("s_waitcnt vmcnt(0)" ::: "memory")
#define VMNONE

  const int nkt = K >> 6;
  const int niter = nkt >> 1;

  STG_A(0, 0, 0); STG_A(0, 1, 0);
  STG_B(0, 0, 0); STG_B(0, 1, 0);
  STG_B(1, 0, 1); STG_B(1, 1, 1);
  asm volatile("s_waitcnt vmcnt(4)" ::: "memory");
  __builtin_amdgcn_s_barrier();

  for (int i = 0; i + 1 < niter; ++i) {
    const int t1 = 2 * i + 1, t2 = 2 * i + 2, t3 = 2 * i + 3;
    bf16x8 bfr[4][2];
    PH(0, 0, STG_A(1, 0, t1), VMNONE)
    PH(0, 1, STG_A(1, 1, t1), VMNONE)
    PH(0, 2, STG_B(0, 0, t2), VMNONE)
    PH(0, 3, STG_B(0, 1, t2), VM2)
    PH(1, 0, STG_A(0, 0, t2), VMNONE)
    PH(1, 1, STG_A(0, 1, t2), VMNONE)
    PH(1, 2, STG_B(1, 0, t3), VMNONE)
    PH(1, 3, STG_B(1, 1, t3), VM2)
  }
  {
    const int t1 = nkt - 1;
    bf16x8 bfr[4][2];
    PH(0, 0, STG_A(1, 0, t1), VMNONE)
    PH(0, 1, STG_A(1, 1, t1), VMNONE)
    PH(0, 2, ((void)0), VMNONE)
    PH(0, 3, ((void)0), VM0)
    PH(1, 0, ((void)0), VMNONE)
    PH(1, 1, ((void)0), VMNONE)
    PH(1, 2, ((void)0), VMNONE)
    PH(1, 3, ((void)0), VMNONE)
  }

#pragma unroll
  for (int m = 0; m < 8; ++m)
#pragma unroll
    for (int n = 0; n < 4; ++n)
#pragma unroll
      for (int r = 0; r < 4; ++r) {
        int row = row0 + wm * 128 + m * 16 + l4 * 4 + r;
        int col = col0 + wn * 64 + n * 16 + l15;
        C[(size_t)row * N + col] = acc[m][n][r];
      }
#undef STG_A
#undef STG_B
#undef PH
#undef VM2
#undef VM0
#undef VMNONE
}

// ---------- RoPE (neox) + per-head RMSNorm ----------
__global__ void k_rope_norm(const float* __restrict__ qkv, const int* __restrict__ pos,
                            const float* __restrict__ wqk,
                            u16* __restrict__ qo, u16* __restrict__ ko) {
  const int wid = (blockIdx.x * blockDim.x + threadIdx.x) >> 6;
  const int lane = threadIdx.x & 63;
  const int s = wid / 48;
  const int r = wid - s * 48;
  const float* src;
  u16* dst;
  const bool isq = (r < NHEAD);
  if (isq) {
    src = qkv + (size_t)s * QKV_COLS + r * HD;
    dst = qo + (size_t)s * (NHEAD * HD) + r * HD;
  } else {
    int kv = r - NHEAD;
    src = qkv + (size_t)s * QKV_COLS + HID + kv * HD;
    dst = ko + (size_t)s * (NKVH * HD) + kv * HD;
  }
  float x1 = src[lane], x2 = src[lane + 64];
  float p = (float)pos[s];
  float ang = p * exp2f(-(float)lane * (18.931568569324174f / 64.0f));
  float sn, cs;
  sincosf(ang, &sn, &cs);
  float y1 = x1 * cs - x2 * sn;
  float y2 = x2 * cs + x1 * sn;
  float ss = y1 * y1 + y2 * y2;
#pragma unroll
  for (int off = 32; off > 0; off >>= 1) ss += __shfl_xor(ss, off);
  float rms = rsqrtf(ss * (1.0f / 128.0f) + 1e-5f);
  float sc = isq ? 0.08838834764831843f : 1.0f;
  dst[lane] = f2bf(y1 * rms * wqk[lane] * sc);
  dst[lane + 64] = f2bf(y2 * rms * wqk[lane + 64] * sc);
}

// ---------- V: [s][6144 + kvh*128 + d] f32 -> Vt[kvh][d][s] bf16 ----------
__global__ void k_vtrans(const float* __restrict__ qkv, u16* __restrict__ vt) {
  __shared__ float t[32][129];
  const int s0 = blockIdx.x * 32;
  const int kv = blockIdx.y;
  for (int i = threadIdx.x; i < 32 * 128; i += 256) {
    int sr = i >> 7, d = i & 127;
    t[sr][d] = qkv[(size_t)(s0 + sr) * QKV_COLS + (HID + NKVH * HD) + kv * HD + d];
  }
  __syncthreads();
  for (int i = threadIdx.x; i < 32 * 128; i += 256) {
    int d = i >> 5, sc = i & 31;
    vt[((size_t)kv * HD + d) * S_LEN + s0 + sc] = f2bf(t[sc][d]);
  }
}

// ---------- causal GQA flash attention: PERSISTENT blocks + atomic LPT queue ----------
// 512 blocks (2/CU), 4 waves; item = (qt desc, head). Wave owns 32 q-rows.
// Same verified COMPUTE core as round 5 (swapped QK^T, in-register P).
__global__ __launch_bounds__(256, 2)
void k_attn(const u16* __restrict__ Q, const u16* __restrict__ Kb,
            const u16* __restrict__ Vt, u16* __restrict__ ctx,
            int* __restrict__ counter) {
  __shared__ __align__(16) u16 Ks[2][KVBLK * HD];
  __shared__ __align__(16) u16 Vs[2][HD * KVBLK];
  __shared__ int s_item;
  const int lane = threadIdx.x & 63;
  const int wave = threadIdx.x >> 6;
  const int l15 = lane & 15, l4 = lane >> 4;
  const int l7 = lane & 7, l8 = lane >> 3;

#define STAGE_KV(KT, BUF, KVH)                                                      \
  do {                                                                             \
    const int key0_ = (KT) * KVBLK;                                                \
    _Pragma("unroll")                                                              \
    for (int i = 0; i < 4; ++i) {                                                  \
      int krow = wave * 16 + i * 4 + l4;                                           \
      int kchunk = l15 ^ (krow & 7);                                               \
      async16(&Ks[BUF][(wave * 16 + i * 4) * HD],                                  \
              Kb + (size_t)(key0_ + krow) * (NKVH * HD) + (KVH) * HD + kchunk * 8);\
    }                                                                              \
    _Pragma("unroll")                                                              \
    for (int i = 0; i < 4; ++i) {                                                  \
      int vrow = wave * 32 + i * 8 + l8;                                           \
      int vchunk = l7 ^ (vrow & 7);                                                \
      async16(&Vs[BUF][(wave * 32 + i * 8) * KVBLK],                               \
              Vt + (size_t)((KVH) * HD + vrow) * S_LEN + key0_ + vchunk * 8);      \
    }                                                                              \
  } while (0)

#define VM8 asm volatile("s_waitcnt vmcnt(8)" ::: "memory")
#define VM0 asm volatile("s_waitcnt vmcnt(0)" ::: "memory")
#define BAR __builtin_amdgcn_s_barrier(); __builtin_amdgcn_sched_barrier(0)

#define COMPUTE(BUF, KT)                                                           \
  {                                                                                \
    const int key0 = (KT) * KVBLK;                                                 \
    f32x4 sa[2][4] = {};                                                           \
    _Pragma("unroll")                                                              \
    for (int n = 0; n < 4; ++n) {                                                  \
      const int krow = n * 16 + l15;                                               \
      const u16* kp = &Ks[BUF][krow * HD];                                         \
      _Pragma("unroll")                                                            \
      for (int c = 0; c < 4; ++c) {                                                \
        bf16x8 kf = *(const bf16x8*)(kp + ((c * 4 + l4) ^ (krow & 7)) * 8);        \
        sa[0][n] = __builtin_amdgcn_mfma_f32_16x16x32_bf16(kf, qf[0][c], sa[0][n], 0, 0, 0); \
        sa[1][n] = __builtin_amdgcn_mfma_f32_16x16x32_bf16(kf, qf[1][c], sa[1][n], 0, 0, 0); \
      }                                                                            \
    }                                                                              \
    const bool domask = (key0 + KVBLK) > qt * QBLK;                                \
    bf16x8 pa[2][2];                                                               \
    _Pragma("unroll")                                                              \
    for (int m2 = 0; m2 < 2; ++m2) {                                               \
      const int qrow = qrow0 + m2 * 16 + l15;                                      \
      if (domask) {                                                                \
        _Pragma("unroll")                                                          \
        for (int n = 0; n < 4; ++n)                                                \
          _Pragma("unroll")                                                        \
          for (int r = 0; r < 4; ++r)                                              \
            if (key0 + n * 16 + l4 * 4 + r > qrow) sa[m2][n][r] = -1e30f;          \
      }                                                                            \
      float mx = sa[m2][0][0];                                                     \
      _Pragma("unroll")                                                            \
      for (int n = 0; n < 4; ++n)                                                  \
        _Pragma("unroll")                                                          \
        for (int r = 0; r < 4; ++r) mx = fmaxf(mx, sa[m2][n][r]);                  \
      mx = fmaxf(mx, __shfl_xor(mx, 16));                                          \
      mx = fmaxf(mx, __shfl_xor(mx, 32));                                          \
      const float mnew = fmaxf(m_run[m2], mx);                                     \
      const float corr = __expf(m_run[m2] - mnew);                                 \
      m_run[m2] = mnew;                                                            \
      float p[4][4];                                                               \
      float sum = 0.f;                                                             \
      _Pragma("unroll")                                                            \
      for (int n = 0; n < 4; ++n)                                                  \
        _Pragma("unroll")                                                          \
        for (int r = 0; r < 4; ++r) { p[n][r] = __expf(sa[m2][n][r] - mnew); sum += p[n][r]; } \
      sum += __shfl_xor(sum, 16);                                                  \
      sum += __shfl_xor(sum, 32);                                                  \
      l_run[m2] = l_run[m2] * corr + sum;                                          \
      _Pragma("unroll")                                                            \
      for (int r = 0; r < 4; ++r) {                                                \
        float cc = __shfl(corr, (lane & 48) + ((lane >> 4) << 2) + r);             \
        _Pragma("unroll")                                                          \
        for (int f2 = 0; f2 < 8; ++f2) oacc[m2][f2][r] *= cc;                      \
      }                                                                            \
      unsigned pkk[4][2];                                                          \
      _Pragma("unroll")                                                            \
      for (int n = 0; n < 4; ++n)                                                  \
        _Pragma("unroll")                                                          \
        for (int hi = 0; hi < 2; ++hi)                                             \
          pkk[n][hi] = (unsigned)f2bf(p[n][2 * hi]) | ((unsigned)f2bf(p[n][2 * hi + 1]) << 16); \
      const int s0l = ((lane >> 4) & 1) * 32 + (lane & 15);                        \
      const bool hiSel = (lane & 32) != 0;                                         \
      _Pragma("unroll")                                                            \
      for (int c2 = 0; c2 < 2; ++c2) {                                             \
        unsigned ox[4];                                                            \
        _Pragma("unroll")                                                          \
        for (int i = 0; i < 4; ++i) {                                              \
          int srcl = s0l + ((i >> 1) << 4);                                        \
          unsigned lo = (unsigned)__shfl((int)pkk[2 * c2][i & 1], srcl);           \
          unsigned hi2 = (unsigned)__shfl((int)pkk[2 * c2 + 1][i & 1], srcl);      \
          ox[i] = hiSel ? hi2 : lo;                                                \
        }                                                                          \
        u32x4 tmp = {ox[0], ox[1], ox[2], ox[3]};                                  \
        pa[m2][c2] = __builtin_bit_cast(bf16x8, tmp);                              \
      }                                                                            \
    }                                                                              \
    _Pragma("unroll")                                                              \
    for (int f2 = 0; f2 < 8; ++f2) {                                               \
      const int vrow = f2 * 16 + l15;                                              \
      const u16* vp = &Vs[BUF][vrow * KVBLK];                                      \
      _Pragma("unroll")                                                            \
      for (int c2 = 0; c2 < 2; ++c2) {                                             \
        bf16x8 vf = *(const bf16x8*)(vp + ((c2 * 4 + l4) ^ (vrow & 7)) * 8);       \
        oacc[0][f2] = __builtin_amdgcn_mfma_f32_16x16x32_bf16(pa[0][c2], vf, oacc[0][f2], 0, 0, 0); \
        oacc[1][f2] = __builtin_amdgcn_mfma_f32_16x16x32_bf16(pa[1][c2], vf, oacc[1][f2], 0, 0, 0); \
      }                                                                            \
    }                                                                              \
  }

  for (;;) {
    if (threadIdx.x == 0) s_item = atomicAdd(counter, 1);
    __syncthreads();   // also orders previous item's LDS reads before restage
    const int item = s_item;
    if (item >= NITEMS) break;
    const int qt = (NQT - 1) - item / NHEAD;   // heaviest-first (LPT)
    const int h = item % NHEAD;
    const int kvh = h / GQA;
    const int qrow0 = qt * QBLK + wave * 32;

    bf16x8 qf[2][4];
#pragma unroll
    for (int c = 0; c < 4; ++c)
#pragma unroll
      for (int m2 = 0; m2 < 2; ++m2)
        qf[m2][c] = *(const bf16x8*)(Q + (size_t)(qrow0 + m2 * 16 + l15) * HID + h * HD + c * 32 + l4 * 8);

    float m_run[2] = {-1e30f, -1e30f};
    float l_run[2] = {0.f, 0.f};
    f32x4 oacc[2][8] = {};

    const int nt = 2 * qt + 2;

    STAGE_KV(0, 0, kvh);
    STAGE_KV(1, 1, kvh);

    int t = 0;
    for (; t + 2 < nt; t += 2) {
      VM8; BAR;
      COMPUTE(0, t)
      BAR;
      STAGE_KV(t + 2, 0, kvh);
      VM8; BAR;
      COMPUTE(1, t + 1)
      BAR;
      if (t + 3 < nt) STAGE_KV(t + 3, 1, kvh);
    }
    VM8; BAR;
    COMPUTE(0, nt - 2)
    VM0; BAR;
    COMPUTE(1, nt - 1)

#pragma unroll
    for (int m2 = 0; m2 < 2; ++m2)
#pragma unroll
      for (int r = 0; r < 4; ++r) {
        float li = 1.0f / __shfl(l_run[m2], (lane & 48) + ((lane >> 4) << 2) + r);
        int row = qrow0 + m2 * 16 + l4 * 4 + r;
#pragma unroll
        for (int f2 = 0; f2 < 8; ++f2)
          ctx[(size_t)row * HID + h * HD + f2 * 16 + l15] = f2bf(oacc[m2][f2][r] * li);
      }
  }
#undef STAGE_KV
#undef VM8
#undef VM0
#undef BAR
#undef COMPUTE
}

extern "C" void kernel_launch(void* const* d_in, const int* in_sizes, int n_in,
                              void* d_out, int out_size, void* d_ws, size_t ws_size,
                              hipStream_t stream) {
  (void)in_sizes; (void)n_in; (void)out_size; (void)ws_size;
  const int* positions = (const int*)d_in[0];
  const float* hs = (const float*)d_in[1];
  const float* Wqkv = (const float*)d_in[2];
  const float* Wo = (const float*)d_in[3];
  const float* wqk = (const float*)d_in[4];
  float* out = (float*)d_out;

  char* ws = (char*)d_ws;
  u16* Wqkv_b = (u16*)ws;                  // [0, 73400320)  dead after GEMM1
  u16* q_b   = (u16*)ws;                   // reuse: [0, 20971520)
  u16* k_b   = (u16*)(ws + 20971520);      // [.., 25165824)
  u16* vt_b  = (u16*)(ws + 25165824);      // [.., 29360128)
  int* cnt   = (int*)(ws + 29360128);      // 4 B (dead Wqkv region at attn time)
  u16* Wo_b  = (u16*)(ws + 73400320);      // [.., 125829120)
  u16* hs_b  = (u16*)(ws + 125829120);     // [.., 146800640)  dead after GEMM1
  u16* ctx_b = hs_b;                       // reuse
  float* qkv = (float*)(ws + 146800640);   // [.., 205520896)

  k_f32_to_bf16<<<2048, 256, 0, stream>>>((const float4*)hs, (uint2*)hs_b, (S_LEN * HID) / 4);
  k_f32_to_bf16<<<2048, 256, 0, stream>>>((const float4*)Wqkv, (uint2*)Wqkv_b, (QKV_COLS * HID) / 4);
  k_f32_to_bf16<<<2048, 256, 0, stream>>>((const float4*)Wo, (uint2*)Wo_b, (HID * HID) / 4);

  k_gemm256<<<dim3((QKV_COLS / 256) * (S_LEN / 256)), 512, 0, stream>>>(
      hs_b, Wqkv_b, qkv, S_LEN, QKV_COLS, HID, QKV_COLS / 256);

  k_rope_norm<<<(S_LEN * 48) / 4, 256, 0, stream>>>(qkv, positions, wqk, q_b, k_b);
  k_vtrans<<<dim3(S_LEN / 32, NKVH), 256, 0, stream>>>(qkv, vt_b);

  hipMemsetAsync(cnt, 0, 4, stream);
  k_attn<<<dim3(512), 256, 0, stream>>>(q_b, k_b, vt_b, ctx_b, cnt);

  k_gemm256<<<dim3((HID / 256) * (S_LEN / 256)), 512, 0, stream>>>(
      ctx_b, Wo_b, out, S_LEN, HID, HID, HID / 256);
}

// Round 8
// 518.036 us; speedup vs baseline: 2.3281x; 1.0412x over previous
//
#include <hip/hip_runtime.h>

typedef unsigned short u16;
typedef __bf16 bf16x8 __attribute__((ext_vector_type(8)));
typedef float f32x4 __attribute__((ext_vector_type(4)));
typedef unsigned u32x4 __attribute__((ext_vector_type(4)));

#define S_LEN 2048
#define HID 5120
#define NHEAD 40
#define NKVH 8
#define HD 128
#define QKV_COLS 7168   // (40 + 2*8) * 128
#define GQA 5
#define QBLK 128
#define KVBLK 64
#define NQT (S_LEN / QBLK)        // 16
#define NITEMS (NQT * NHEAD)      // 640

// RNE f32 -> bf16
__device__ __forceinline__ u16 f2bf(float f) {
  unsigned u = __float_as_uint(f);
  u += 0x7FFFu + ((u >> 16) & 1u);
  return (u16)(u >> 16);
}

// async global->LDS, 16B per lane; LDS base must be wave-uniform
__device__ __forceinline__ void async16(void* lds, const void* g) {
  __builtin_amdgcn_global_load_lds(
      (const __attribute__((address_space(1))) unsigned int*)g,
      (__attribute__((address_space(3))) unsigned int*)lds, 16, 0, 0);
}

// ---------- f32 -> bf16 elementwise convert ----------
__global__ void k_f32_to_bf16(const float4* __restrict__ in, uint2* __restrict__ out, int n4) {
  int i = blockIdx.x * blockDim.x + threadIdx.x;
  int stride = gridDim.x * blockDim.x;
  for (; i < n4; i += stride) {
    float4 v = in[i];
    uint2 o;
    o.x = (unsigned)f2bf(v.x) | ((unsigned)f2bf(v.y) << 16);
    o.y = (unsigned)f2bf(v.z) | ((unsigned)f2bf(v.w) << 16);
    out[i] = o;
  }
}

// ---------- 256x256 GEMM, 8 phases/pair, ONE barrier per phase ----------
// Round-8 changes: (1) MFMA k-chunk OUTER loop (dependency distance 8, was 1);
// (2) by = swz%8 so each XCD owns a B-column strip (B k-window L2-resident,
//     read 8x from L2 instead of 8x from L3/HBM).
__global__ __launch_bounds__(512, 2)
void k_gemm256(const u16* __restrict__ A, const u16* __restrict__ B,
               float* __restrict__ C, int M, int N, int K, int gx) {
  __shared__ __align__(16) u16 As[2][2][128 * 64];
  __shared__ __align__(16) u16 Bs[2][2][128 * 64];
  const int tid = threadIdx.x;
  const int wave = tid >> 6, lane = tid & 63;
  const int l15 = lane & 15, l4 = lane >> 4;
  const int wm = wave >> 2, wn = wave & 3;

  const int nwg = gridDim.x;
  int f = blockIdx.x;
  int swz = (nwg % 8 == 0) ? ((f & 7) * (nwg >> 3) + (f >> 3)) : f;
  // by-minor: XCD's contiguous swz chunk spans all 8 M-rows x ~gx/8 B-columns
  const int by = swz & 7, bx = swz >> 3;
  const int row0 = by * 256, col0 = bx * 256;

  const int srow = tid >> 3;
  const int sgch = ((tid & 7) ^ (srow & 7)) * 8;
  const int s7 = l15 & 7;
  const int ch0 = (l4 ^ s7) * 8;
  const int ch1 = ((4 + l4) ^ s7) * 8;

  f32x4 acc[8][4] = {};

#define STG_A(buf, half, kt)                                                        \
  do {                                                                              \
    const size_t k0_ = (size_t)(kt) * 64;                                           \
    async16(&As[buf][half][(wave * 8) * 64],                                        \
            A + (size_t)(row0 + (half) * 128 + srow) * K + k0_ + sgch);             \
    async16(&As[buf][half][(64 + wave * 8) * 64],                                   \
            A + (size_t)(row0 + (half) * 128 + 64 + srow) * K + k0_ + sgch);        \
  } while (0)
#define STG_B(buf, half, kt)                                                        \
  do {                                                                              \
    const size_t k0_ = (size_t)(kt) * 64;                                           \
    async16(&Bs[buf][half][(wave * 8) * 64],                                        \
            B + (size_t)(col0 + (half) * 128 + srow) * K + k0_ + sgch);             \
    async16(&Bs[buf][half][(64 + wave * 8) * 64],                                   \
            B + (size_t)(col0 + (half) * 128 + 64 + srow) * K + k0_ + sgch);        \
  } while (0)

#define PH(buf, q, STAGE, VM)                                                       \
  {                                                                                 \
    bf16x8 af[2][2];                                                                \
    _Pragma("unroll") for (int e = 0; e < 2; ++e) {                                 \
      const u16* pa = &As[buf][wm][((2 * (q) + e) * 16 + l15) * 64];                \
      af[e][0] = *(const bf16x8*)(pa + ch0);                                        \
      af[e][1] = *(const bf16x8*)(pa + ch1);                                        \
    }                                                                               \
    if ((q) == 0) {                                                                 \
      _Pragma("unroll") for (int n = 0; n < 4; ++n) {                               \
        const u16* pb = &Bs[buf][wn >> 1][((wn & 1) * 64 + n * 16 + l15) * 64];     \
        bfr[n][0] = *(const bf16x8*)(pb + ch0);                                     \
        bfr[n][1] = *(const bf16x8*)(pb + ch1);                                     \
      }                                                                             \
    }                                                                               \
    VM;                                                                             \
    __builtin_amdgcn_s_barrier();                                                   \
    asm volatile("s_waitcnt lgkmcnt(0)" ::: "memory");                              \
    __builtin_amdgcn_sched_barrier(0);                                              \
    STAGE;                                                                          \
    __builtin_amdgcn_s_setprio(1);                                                  \
    _Pragma("unroll") for (int kk = 0; kk < 2; ++kk)                                \
      _Pragma("unroll") for (int e = 0; e < 2; ++e)                                 \
        _Pragma("unroll") for (int n = 0; n < 4; ++n)                               \
          acc[2 * (q) + e][n] = __builtin_amdgcn_mfma_f32_16x16x32_bf16(            \
              af[e][kk], bfr[n][kk], acc[2 * (q) + e][n], 0, 0, 0);                 \
    __builtin_amdgcn_s_setprio(0);                                                  \
  }
#define VM2 asm volatile("s_waitcnt vmcnt(2)" ::: "memory")
#define VM0 asm volatile("s_waitcnt vmcnt(0)" ::: "memory")
#define VMNONE

  const int nkt = K >> 6;
  const int niter = nkt >> 1;

  STG_A(0, 0, 0); STG_A(0, 1, 0);
  STG_B(0, 0, 0); STG_B(0, 1, 0);
  STG_B(1, 0, 1); STG_B(1, 1, 1);
  asm volatile("s_waitcnt vmcnt(4)" ::: "memory");
  __builtin_amdgcn_s_barrier();

  for (int i = 0; i + 1 < niter; ++i) {
    const int t1 = 2 * i + 1, t2 = 2 * i + 2, t3 = 2 * i + 3;
    bf16x8 bfr[4][2];
    PH(0, 0, STG_A(1, 0, t1), VMNONE)
    PH(0, 1, STG_A(1, 1, t1), VMNONE)
    PH(0, 2, STG_B(0, 0, t2), VMNONE)
    PH(0, 3, STG_B(0, 1, t2), VM2)
    PH(1, 0, STG_A(0, 0, t2), VMNONE)
    PH(1, 1, STG_A(0, 1, t2), VMNONE)
    PH(1, 2, STG_B(1, 0, t3), VMNONE)
    PH(1, 3, STG_B(1, 1, t3), VM2)
  }
  {
    const int t1 = nkt - 1;
    bf16x8 bfr[4][2];
    PH(0, 0, STG_A(1, 0, t1), VMNONE)
    PH(0, 1, STG_A(1, 1, t1), VMNONE)
    PH(0, 2, ((void)0), VMNONE)
    PH(0, 3, ((void)0), VM0)
    PH(1, 0, ((void)0), VMNONE)
    PH(1, 1, ((void)0), VMNONE)
    PH(1, 2, ((void)0), VMNONE)
    PH(1, 3, ((void)0), VMNONE)
  }

#pragma unroll
  for (int m = 0; m < 8; ++m)
#pragma unroll
    for (int n = 0; n < 4; ++n)
#pragma unroll
      for (int r = 0; r < 4; ++r) {
        int row = row0 + wm * 128 + m * 16 + l4 * 4 + r;
        int col = col0 + wn * 64 + n * 16 + l15;
        C[(size_t)row * N + col] = acc[m][n][r];
      }
#undef STG_A
#undef STG_B
#undef PH
#undef VM2
#undef VM0
#undef VMNONE
}

// ---------- RoPE (neox) + per-head RMSNorm ----------
__global__ void k_rope_norm(const float* __restrict__ qkv, const int* __restrict__ pos,
                            const float* __restrict__ wqk,
                            u16* __restrict__ qo, u16* __restrict__ ko) {
  const int wid = (blockIdx.x * blockDim.x + threadIdx.x) >> 6;
  const int lane = threadIdx.x & 63;
  const int s = wid / 48;
  const int r = wid - s * 48;
  const float* src;
  u16* dst;
  const bool isq = (r < NHEAD);
  if (isq) {
    src = qkv + (size_t)s * QKV_COLS + r * HD;
    dst = qo + (size_t)s * (NHEAD * HD) + r * HD;
  } else {
    int kv = r - NHEAD;
    src = qkv + (size_t)s * QKV_COLS + HID + kv * HD;
    dst = ko + (size_t)s * (NKVH * HD) + kv * HD;
  }
  float x1 = src[lane], x2 = src[lane + 64];
  float p = (float)pos[s];
  float ang = p * exp2f(-(float)lane * (18.931568569324174f / 64.0f));
  float sn, cs;
  sincosf(ang, &sn, &cs);
  float y1 = x1 * cs - x2 * sn;
  float y2 = x2 * cs + x1 * sn;
  float ss = y1 * y1 + y2 * y2;
#pragma unroll
  for (int off = 32; off > 0; off >>= 1) ss += __shfl_xor(ss, off);
  float rms = rsqrtf(ss * (1.0f / 128.0f) + 1e-5f);
  float sc = isq ? 0.08838834764831843f : 1.0f;
  dst[lane] = f2bf(y1 * rms * wqk[lane] * sc);
  dst[lane + 64] = f2bf(y2 * rms * wqk[lane + 64] * sc);
}

// ---------- V: [s][6144 + kvh*128 + d] f32 -> Vt[kvh][d][s] bf16 ----------
__global__ void k_vtrans(const float* __restrict__ qkv, u16* __restrict__ vt) {
  __shared__ float t[32][129];
  const int s0 = blockIdx.x * 32;
  const int kv = blockIdx.y;
  for (int i = threadIdx.x; i < 32 * 128; i += 256) {
    int sr = i >> 7, d = i & 127;
    t[sr][d] = qkv[(size_t)(s0 + sr) * QKV_COLS + (HID + NKVH * HD) + kv * HD + d];
  }
  __syncthreads();
  for (int i = threadIdx.x; i < 32 * 128; i += 256) {
    int d = i >> 5, sc = i & 31;
    vt[((size_t)kv * HD + d) * S_LEN + s0 + sc] = f2bf(t[sc][d]);
  }
}

// ---------- causal GQA flash attention: persistent blocks + atomic LPT queue ----------
// Round-8 change: MFMA interleave — c/c2 chunk loops moved OUTER so dependent
// accumulator updates are 8/16 apart instead of 2.
__global__ __launch_bounds__(256, 2)
void k_attn(const u16* __restrict__ Q, const u16* __restrict__ Kb,
            const u16* __restrict__ Vt, u16* __restrict__ ctx,
            int* __restrict__ counter) {
  __shared__ __align__(16) u16 Ks[2][KVBLK * HD];
  __shared__ __align__(16) u16 Vs[2][HD * KVBLK];
  __shared__ int s_item;
  const int lane = threadIdx.x & 63;
  const int wave = threadIdx.x >> 6;
  const int l15 = lane & 15, l4 = lane >> 4;
  const int l7 = lane & 7, l8 = lane >> 3;

#define STAGE_KV(KT, BUF, KVH)                                                      \
  do {                                                                             \
    const int key0_ = (KT) * KVBLK;                                                \
    _Pragma("unroll")                                                              \
    for (int i = 0; i < 4; ++i) {                                                  \
      int krow = wave * 16 + i * 4 + l4;                                           \
      int kchunk = l15 ^ (krow & 7);                                               \
      async16(&Ks[BUF][(wave * 16 + i * 4) * HD],                                  \
              Kb + (size_t)(key0_ + krow) * (NKVH * HD) + (KVH) * HD + kchunk * 8);\
    }                                                                              \
    _Pragma("unroll")                                                              \
    for (int i = 0; i < 4; ++i) {                                                  \
      int vrow = wave * 32 + i * 8 + l8;                                           \
      int vchunk = l7 ^ (vrow & 7);                                                \
      async16(&Vs[BUF][(wave * 32 + i * 8) * KVBLK],                               \
              Vt + (size_t)((KVH) * HD + vrow) * S_LEN + key0_ + vchunk * 8);      \
    }                                                                              \
  } while (0)

#define VM8 asm volatile("s_waitcnt vmcnt(8)" ::: "memory")
#define VM0 asm volatile("s_waitcnt vmcnt(0)" ::: "memory")
#define BAR __builtin_amdgcn_s_barrier(); __builtin_amdgcn_sched_barrier(0)

#define COMPUTE(BUF, KT)                                                           \
  {                                                                                \
    const int key0 = (KT) * KVBLK;                                                 \
    f32x4 sa[2][4] = {};                                                           \
    _Pragma("unroll")                                                              \
    for (int c = 0; c < 4; ++c) {                                                  \
      _Pragma("unroll")                                                            \
      for (int n = 0; n < 4; ++n) {                                                \
        const int krow = n * 16 + l15;                                             \
        bf16x8 kf = *(const bf16x8*)(&Ks[BUF][krow * HD + ((c * 4 + l4) ^ (krow & 7)) * 8]); \
        sa[0][n] = __builtin_amdgcn_mfma_f32_16x16x32_bf16(kf, qf[0][c], sa[0][n], 0, 0, 0); \
        sa[1][n] = __builtin_amdgcn_mfma_f32_16x16x32_bf16(kf, qf[1][c], sa[1][n], 0, 0, 0); \
      }                                                                            \
    }                                                                              \
    const bool domask = (key0 + KVBLK) > qt * QBLK;                                \
    bf16x8 pa[2][2];                                                               \
    _Pragma("unroll")                                                              \
    for (int m2 = 0; m2 < 2; ++m2) {                                               \
      const int qrow = qrow0 + m2 * 16 + l15;                                      \
      if (domask) {                                                                \
        _Pragma("unroll")                                                          \
        for (int n = 0; n < 4; ++n)                                                \
          _Pragma("unroll")                                                        \
          for (int r = 0; r < 4; ++r)                                              \
            if (key0 + n * 16 + l4 * 4 + r > qrow) sa[m2][n][r] = -1e30f;          \
      }                                                                            \
      float mx = sa[m2][0][0];                                                     \
      _Pragma("unroll")                                                            \
      for (int n = 0; n < 4; ++n)                                                  \
        _Pragma("unroll")                                                          \
        for (int r = 0; r < 4; ++r) mx = fmaxf(mx, sa[m2][n][r]);                  \
      mx = fmaxf(mx, __shfl_xor(mx, 16));                                          \
      mx = fmaxf(mx, __shfl_xor(mx, 32));                                          \
      const float mnew = fmaxf(m_run[m2], mx);                                     \
      const float corr = __expf(m_run[m2] - mnew);                                 \
      m_run[m2] = mnew;                                                            \
      float p[4][4];                                                               \
      float sum = 0.f;                                                             \
      _Pragma("unroll")                                                            \
      for (int n = 0; n < 4; ++n)                                                  \
        _Pragma("unroll")                                                          \
        for (int r = 0; r < 4; ++r) { p[n][r] = __expf(sa[m2][n][r] - mnew); sum += p[n][r]; } \
      sum += __shfl_xor(sum, 16);                                                  \
      sum += __shfl_xor(sum, 32);                                                  \
      l_run[m2] = l_run[m2] * corr + sum;                                          \
      _Pragma("unroll")                                                            \
      for (int r = 0; r < 4; ++r) {                                                \
        float cc = __shfl(corr, (lane & 48) + ((lane >> 4) << 2) + r);             \
        _Pragma("unroll")                                                          \
        for (int f2 = 0; f2 < 8; ++f2) oacc[m2][f2][r] *= cc;                      \
      }                                                                            \
      unsigned pkk[4][2];                                                          \
      _Pragma("unroll")                                                            \
      for (int n = 0; n < 4; ++n)                                                  \
        _Pragma("unroll")                                                          \
        for (int hi = 0; hi < 2; ++hi)                                             \
          pkk[n][hi] = (unsigned)f2bf(p[n][2 * hi]) | ((unsigned)f2bf(p[n][2 * hi + 1]) << 16); \
      const int s0l = ((lane >> 4) & 1) * 32 + (lane & 15);                        \
      const bool hiSel = (lane & 32) != 0;                                         \
      _Pragma("unroll")                                                            \
      for (int c2 = 0; c2 < 2; ++c2) {                                             \
        unsigned ox[4];                                                            \
        _Pragma("unroll")                                                          \
        for (int i = 0; i < 4; ++i) {                                              \
          int srcl = s0l + ((i >> 1) << 4);                                        \
          unsigned lo = (unsigned)__shfl((int)pkk[2 * c2][i & 1], srcl);           \
          unsigned hi2 = (unsigned)__shfl((int)pkk[2 * c2 + 1][i & 1], srcl);      \
          ox[i] = hiSel ? hi2 : lo;                                                \
        }                                                                          \
        u32x4 tmp = {ox[0], ox[1], ox[2], ox[3]};                                  \
        pa[m2][c2] = __builtin_bit_cast(bf16x8, tmp);                              \
      }                                                                            \
    }                                                                              \
    _Pragma("unroll")                                                              \
    for (int c2 = 0; c2 < 2; ++c2) {                                               \
      _Pragma("unroll")                                                            \
      for (int f2 = 0; f2 < 8; ++f2) {                                             \
        const int vrow = f2 * 16 + l15;                                            \
        bf16x8 vf = *(const bf16x8*)(&Vs[BUF][vrow * KVBLK + ((c2 * 4 + l4) ^ (vrow & 7)) * 8]); \
        oacc[0][f2] = __builtin_amdgcn_mfma_f32_16x16x32_bf16(pa[0][c2], vf, oacc[0][f2], 0, 0, 0); \
        oacc[1][f2] = __builtin_amdgcn_mfma_f32_16x16x32_bf16(pa[1][c2], vf, oacc[1][f2], 0, 0, 0); \
      }                                                                            \
    }                                                                              \
  }

  for (;;) {
    if (threadIdx.x == 0) s_item = atomicAdd(counter, 1);
    __syncthreads();   // also orders previous item's LDS reads before restage
    const int item = s_item;
    if (item >= NITEMS) break;
    const int qt = (NQT - 1) - item / NHEAD;   // heaviest-first (LPT)
    const int h = item % NHEAD;
    const int kvh = h / GQA;
    const int qrow0 = qt * QBLK + wave * 32;

    bf16x8 qf[2][4];
#pragma unroll
    for (int c = 0; c < 4; ++c)
#pragma unroll
      for (int m2 = 0; m2 < 2; ++m2)
        qf[m2][c] = *(const bf16x8*)(Q + (size_t)(qrow0 + m2 * 16 + l15) * HID + h * HD + c * 32 + l4 * 8);

    float m_run[2] = {-1e30f, -1e30f};
    float l_run[2] = {0.f, 0.f};
    f32x4 oacc[2][8] = {};

    const int nt = 2 * qt + 2;

    STAGE_KV(0, 0, kvh);
    STAGE_KV(1, 1, kvh);

    int t = 0;
    for (; t + 2 < nt; t += 2) {
      VM8; BAR;
      COMPUTE(0, t)
      BAR;
      STAGE_KV(t + 2, 0, kvh);
      VM8; BAR;
      COMPUTE(1, t + 1)
      BAR;
      if (t + 3 < nt) STAGE_KV(t + 3, 1, kvh);
    }
    VM8; BAR;
    COMPUTE(0, nt - 2)
    VM0; BAR;
    COMPUTE(1, nt - 1)

#pragma unroll
    for (int m2 = 0; m2 < 2; ++m2)
#pragma unroll
      for (int r = 0; r < 4; ++r) {
        float li = 1.0f / __shfl(l_run[m2], (lane & 48) + ((lane >> 4) << 2) + r);
        int row = qrow0 + m2 * 16 + l4 * 4 + r;
#pragma unroll
        for (int f2 = 0; f2 < 8; ++f2)
          ctx[(size_t)row * HID + h * HD + f2 * 16 + l15] = f2bf(oacc[m2][f2][r] * li);
      }
  }
#undef STAGE_KV
#undef VM8
#undef VM0
#undef BAR
#undef COMPUTE
}

extern "C" void kernel_launch(void* const* d_in, const int* in_sizes, int n_in,
                              void* d_out, int out_size, void* d_ws, size_t ws_size,
                              hipStream_t stream) {
  (void)in_sizes; (void)n_in; (void)out_size; (void)ws_size;
  const int* positions = (const int*)d_in[0];
  const float* hs = (const float*)d_in[1];
  const float* Wqkv = (const float*)d_in[2];
  const float* Wo = (const float*)d_in[3];
  const float* wqk = (const float*)d_in[4];
  float* out = (float*)d_out;

  char* ws = (char*)d_ws;
  u16* Wqkv_b = (u16*)ws;                  // [0, 73400320)  dead after GEMM1
  u16* q_b   = (u16*)ws;                   // reuse: [0, 20971520)
  u16* k_b   = (u16*)(ws + 20971520);      // [.., 25165824)
  u16* vt_b  = (u16*)(ws + 25165824);      // [.., 29360128)
  int* cnt   = (int*)(ws + 29360128);      // 4 B (dead Wqkv region at attn time)
  u16* Wo_b  = (u16*)(ws + 73400320);      // [.., 125829120)
  u16* hs_b  = (u16*)(ws + 125829120);     // [.., 146800640)  dead after GEMM1
  u16* ctx_b = hs_b;                       // reuse
  float* qkv = (float*)(ws + 146800640);   // [.., 205520896)

  k_f32_to_bf16<<<2048, 256, 0, stream>>>((const float4*)hs, (uint2*)hs_b, (S_LEN * HID) / 4);
  k_f32_to_bf16<<<2048, 256, 0, stream>>>((const float4*)Wqkv, (uint2*)Wqkv_b, (QKV_COLS * HID) / 4);
  k_f32_to_bf16<<<2048, 256, 0, stream>>>((const float4*)Wo, (uint2*)Wo_b, (HID * HID) / 4);

  k_gemm256<<<dim3((QKV_COLS / 256) * (S_LEN / 256)), 512, 0, stream>>>(
      hs_b, Wqkv_b, qkv, S_LEN, QKV_COLS, HID, QKV_COLS / 256);

  k_rope_norm<<<(S_LEN * 48) / 4, 256, 0, stream>>>(qkv, positions, wqk, q_b, k_b);
  k_vtrans<<<dim3(S_LEN / 32, NKVH), 256, 0, stream>>>(qkv, vt_b);

  hipMemsetAsync(cnt, 0, 4, stream);
  k_attn<<<dim3(512), 256, 0, stream>>>(q_b, k_b, vt_b, ctx_b, cnt);

  k_gemm256<<<dim3((HID / 256) * (S_LEN / 256)), 512, 0, stream>>>(
      ctx_b, Wo_b, out, S_LEN, HID, HID, HID / 256);
}